// Round 6
// baseline (439.402 us; speedup 1.0000x reference)
//
#include <hip/hip_runtime.h>
#include <stdint.h>

typedef __bf16 bf16;
typedef float f32x4 __attribute__((ext_vector_type(4)));
typedef bf16 bf16x8 __attribute__((ext_vector_type(8)));
typedef bf16 bf16x4 __attribute__((ext_vector_type(4)));

#define MFMA16(a, b, c) __builtin_amdgcn_mfma_f32_16x16x32_bf16((a), (b), (c), 0, 0, 0)
#define EXP2F(x) __builtin_amdgcn_exp2f(x)

__device__ __forceinline__ void gll16(const void* g, void* l) {
  __builtin_amdgcn_global_load_lds((const __attribute__((address_space(1))) void*)g,
                                   (__attribute__((address_space(3))) void*)l, 16, 0, 0);
}

// ---------------------------------------------------------------------------
// fp32 -> bf16 conversion of all tensors, one launch.
// ---------------------------------------------------------------------------
__global__ __launch_bounds__(256) void convert_all(
    const float4* __restrict__ Q, const float4* __restrict__ K, const float4* __restrict__ V,
    const float4* __restrict__ Wq, const float4* __restrict__ Wk, const float4* __restrict__ Wv,
    const float4* __restrict__ fcw, const float4* __restrict__ E,
    bf16x4* __restrict__ Xq, bf16x4* __restrict__ Xk, bf16x4* __restrict__ Xv,
    bf16x4* __restrict__ Wqb, bf16x4* __restrict__ Wkb, bf16x4* __restrict__ Wvb,
    bf16x4* __restrict__ fcb, bf16x4* __restrict__ Eb) {
  int i = blockIdx.x * 256 + threadIdx.x;
  const float4* s;
  bf16x4* d;
  int off;
  if (i < 1048576) { s = Q; d = Xq; off = i; }
  else if (i < 2097152) { s = K; d = Xk; off = i - 1048576; }
  else if (i < 3145728) { s = V; d = Xv; off = i - 2097152; }
  else if (i < 3211264) { s = Wq; d = Wqb; off = i - 3145728; }
  else if (i < 3276800) { s = Wk; d = Wkb; off = i - 3211264; }
  else if (i < 3342336) { s = Wv; d = Wvb; off = i - 3276800; }
  else if (i < 3407872) { s = fcw; d = fcb; off = i - 3342336; }
  else { s = E; d = Eb; off = i - 3407872; }
  float4 v = s[off];
  bf16x4 o;
  o[0] = (bf16)v.x; o[1] = (bf16)v.y; o[2] = (bf16)v.z; o[3] = (bf16)v.w;
  d[off] = o;
}

// ---------------------------------------------------------------------------
// GEMM core: C[128x128] = A[128x512] * Bt[128x512]^T (row-major bf16).
// ---------------------------------------------------------------------------
__device__ __forceinline__ void gemm_core(const bf16* __restrict__ A, const bf16* __restrict__ Bt,
                                          bf16* ldsA, bf16* ldsB, int m0, int n0,
                                          f32x4 acc[4][4]) {
  const int t = threadIdx.x;
  const int lane = t & 63, w = t >> 6;
  const int l15 = lane & 15, quad = lane >> 4;
  const int wm = w >> 1, wn = w & 1;
#pragma unroll
  for (int i = 0; i < 4; i++)
#pragma unroll
    for (int j = 0; j < 4; j++) acc[i][j] = (f32x4){0.f, 0.f, 0.f, 0.f};

  const int ch0 = t, ch1 = t + 256;
  const int r0 = ch0 >> 2, c0 = (ch0 & 3) ^ (r0 & 3);
  const int r1 = ch1 >> 2, c1 = (ch1 & 3) ^ (r1 & 3);

  int aoff[4], boff[4];
#pragma unroll
  for (int mt = 0; mt < 4; mt++) {
    int m = wm * 64 + mt * 16 + l15;
    aoff[mt] = (m << 6) + ((quad ^ (l15 & 3)) << 4);
    int n = wn * 64 + mt * 16 + l15;
    boff[mt] = (n << 6) + ((quad ^ (l15 & 3)) << 4);
  }
  bf16* ldsA1 = ldsA + w * 512;
  bf16* ldsA2 = ldsA + 2048 + w * 512;
  bf16* ldsB1 = ldsB + w * 512;
  bf16* ldsB2 = ldsB + 2048 + w * 512;

  for (int kt = 0; kt < 512; kt += 32) {
    gll16(A + (size_t)(m0 + r0) * 512 + kt + c0 * 8, ldsA1);
    gll16(A + (size_t)(m0 + r1) * 512 + kt + c1 * 8, ldsA2);
    gll16(Bt + (size_t)(n0 + r0) * 512 + kt + c0 * 8, ldsB1);
    gll16(Bt + (size_t)(n0 + r1) * 512 + kt + c1 * 8, ldsB2);
    __syncthreads();
    bf16x8 af[4], bfr[4];
#pragma unroll
    for (int mt = 0; mt < 4; mt++) af[mt] = *(const bf16x8*)((const char*)ldsA + aoff[mt]);
#pragma unroll
    for (int nt = 0; nt < 4; nt++) bfr[nt] = *(const bf16x8*)((const char*)ldsB + boff[nt]);
#pragma unroll
    for (int mt = 0; mt < 4; mt++)
#pragma unroll
      for (int nt = 0; nt < 4; nt++)
        acc[mt][nt] = MFMA16(af[mt], bfr[nt], acc[mt][nt]);
    __syncthreads();
  }
}

// proj_gemm: z==0/1 write q/k in (B,H,L,64). z==2 writes v DIRECTLY TRANSPOSED
// into vT (B,H,64,L) via an LDS-staged transpose (two 64-col halves reusing
// the 17.4KB smem), with fully coalesced bf16x8 stores along l.
__global__ __launch_bounds__(256) void proj_gemm(
    const bf16* __restrict__ Xq, const bf16* __restrict__ Xk, const bf16* __restrict__ Xv,
    const bf16* __restrict__ Wq, const bf16* __restrict__ Wk, const bf16* __restrict__ Wv,
    const float* __restrict__ bq, const float* __restrict__ bk, const float* __restrict__ bv,
    bf16* __restrict__ qb, bf16* __restrict__ kb, bf16* __restrict__ vT) {
  __shared__ __align__(16) char smem[17408];  // gemm: 2x8KB; transpose: 64x136 bf16
  bf16* ldsA = (bf16*)smem;
  bf16* ldsB = (bf16*)(smem + 8192);
  const int z = blockIdx.z;
  const bf16* A = z == 0 ? Xq : (z == 1 ? Xk : Xv);
  const bf16* W = z == 0 ? Wq : (z == 1 ? Wk : Wv);
  const float* bias = z == 0 ? bq : (z == 1 ? bk : bv);
  const int m0 = blockIdx.x * 128, n0 = blockIdx.y * 128;
  f32x4 acc[4][4];
  gemm_core(A, W, ldsA, ldsB, m0, n0, acc);

  const int t = threadIdx.x;
  const int lane = t & 63, w = t >> 6;
  const int l15 = lane & 15, quad = lane >> 4;
  const int wm = w >> 1, wn = w & 1;
  if (z == 2) {
    // ---- transposed epilogue: two halves over n (64 cols = one head each) --
    bf16* T = (bf16*)smem;  // [64][136]
    const int b = m0 >> 11, l0 = m0 & 2047, h0 = n0 >> 6;
#pragma unroll
    for (int half = 0; half < 2; half++) {
      __syncthreads();  // prev half's readers done / gemm LDS free
      if (wn == half) {
#pragma unroll
        for (int mt = 0; mt < 4; mt++)
#pragma unroll
          for (int nt = 0; nt < 4; nt++) {
            int n_loc = nt * 16 + l15;  // = d
            int mch = wm * 64 + mt * 16 + quad * 4;
            float bi = bias[n0 + half * 64 + n_loc];
            bf16x4 pv;
#pragma unroll
            for (int r = 0; r < 4; r++) pv[r] = (bf16)(acc[mt][nt][r] + bi);
            *(bf16x4*)&T[n_loc * 136 + mch] = pv;
          }
      }
      __syncthreads();
      bf16* dsth = vT + ((size_t)((b * 8 + h0 + half) * 64)) * 2048 + l0;
#pragma unroll
      for (int p = 0; p < 4; p++) {
        int id = t + 256 * p;      // 1024 chunks: 64 d-rows x 16 l-chunks
        int d = id >> 4, c = id & 15;
        bf16x8 v = *(const bf16x8*)&T[d * 136 + c * 8];
        *(bf16x8*)&dsth[(size_t)d * 2048 + c * 8] = v;
      }
    }
  } else {
    bf16* out = z == 0 ? qb : kb;
#pragma unroll
    for (int mt = 0; mt < 4; mt++)
#pragma unroll
      for (int nt = 0; nt < 4; nt++)
#pragma unroll
        for (int r = 0; r < 4; r++) {
          int gm = m0 + wm * 64 + mt * 16 + quad * 4 + r;
          int gn = n0 + wn * 64 + nt * 16 + l15;
          float v = acc[mt][nt][r] + bias[gn];
          int b = gm >> 11, l = gm & 2047, h = gn >> 6, d = gn & 63;
          out[(((size_t)(b * 8 + h)) * 2048 + l) * 64 + d] = (bf16)v;
        }
  }
}

__global__ __launch_bounds__(256) void final_gemm(const bf16* __restrict__ A,
                                                  const bf16* __restrict__ W,
                                                  const float* __restrict__ bias,
                                                  float* __restrict__ out) {
  __shared__ bf16 ldsA[128 * 32];
  __shared__ bf16 ldsB[128 * 32];
  const int m0 = blockIdx.x * 128, n0 = blockIdx.y * 128;
  f32x4 acc[4][4];
  gemm_core(A, W, ldsA, ldsB, m0, n0, acc);

  const int t = threadIdx.x;
  const int lane = t & 63, w = t >> 6;
  const int l15 = lane & 15, quad = lane >> 4;
  const int wm = w >> 1, wn = w & 1;
#pragma unroll
  for (int mt = 0; mt < 4; mt++)
#pragma unroll
    for (int nt = 0; nt < 4; nt++)
#pragma unroll
      for (int r = 0; r < 4; r++) {
        int gm = m0 + wm * 64 + mt * 16 + quad * 4 + r;
        int gn = n0 + wn * 64 + nt * 16 + l15;
        out[(size_t)gm * 512 + gn] = acc[mt][nt][r] + bias[gn];
      }
}

// ---------------------------------------------------------------------------
// Flash attention + relative position, causal. R6: BARRIER-FREE tile loop.
// K and vT per-bh slices are 256KB each -> fully L2-resident, so LDS staging
// of K/V was pure overhead (guide m169); MFMA fragments read K/V DIRECTLY
// from global (fragment address = global address; the old staging swizzle
// cancels). P stays in per-wave-private LDS (lgkm-ordered, no barrier).
// LDS 9.2KB (P only) + <=64 VGPR -> 8 blocks/CU, waves free-run (no convoy).
// Jobs (48 per bh, grid 1536, all <=16 tiles, LPT order) unchanged.
// ---------------------------------------------------------------------------
__global__ __launch_bounds__(256, 8) void attn_kernel(
    const bf16* __restrict__ qbuf, const bf16* __restrict__ kbuf,
    const bf16* __restrict__ vT, const bf16* __restrict__ Eb,
    bf16* __restrict__ attnb, bf16* __restrict__ Of1,
    float* __restrict__ Os0, float* __restrict__ Os1) {
  __shared__ bf16 Pl[4][16 * 72];
  const int t = threadIdx.x, w = t >> 6, lane = t & 63;
  const int l15 = lane & 15, quad = lane >> 4;
  const int x = blockIdx.x;
  const int bh = x & 31, job = x >> 5;
  int strip, jt0, jt1;
  bool isB;
  if (job < 16) {
    strip = 16 + job; jt0 = 0; jt1 = 16; isB = false;
  } else {
    int k = job - 16, i = k >> 1;
    if ((k & 1) == 0) { strip = 15 - i; jt0 = 0; jt1 = 16 - i; isB = false; }
    else { strip = 31 - i; jt0 = 16; jt1 = 32 - i; isB = true; }
  }
  const int i0 = strip * 64 + w * 16;  // this wave's 16 q-rows
  bf16* Pw = Pl[w];
  const bf16* qh = qbuf + (size_t)bh * 2048 * 64;
  const bf16* kh = kbuf + (size_t)bh * 2048 * 64;
  const bf16* vh = vT + (size_t)bh * 64 * 2048;

  // bpermute lane addresses + tile-select mask, per acc register r
  int bpaddr[4];
  bool loA[4];
#pragma unroll
  for (int r = 0; r < 4; r++) {
    int u = quad * 4 + r;
    bpaddr[r] = (((l15 + 15 - u) & 15) + 16 * quad) * 4;
    loA[r] = (l15 <= u);  // source tile nt (else nt+1)
  }

  bf16x8 aq0, aq1;
  {
    const bf16* qrow = qh + (size_t)(i0 + l15) * 64 + quad * 8;
    aq0 = *(const bf16x8*)qrow;
    aq1 = *(const bf16x8*)(qrow + 32);
  }
  bf16x8 ones;
#pragma unroll
  for (int j = 0; j < 8; j++) ones[j] = (bf16)1.0f;

  f32x4 O[4], Osum;
  Osum = (f32x4){0.f, 0.f, 0.f, 0.f};
#pragma unroll
  for (int i = 0; i < 4; i++) O[i] = (f32x4){0.f, 0.f, 0.f, 0.f};
  const float sc = 0.125f * 1.44269504088896f;  // 1/sqrt(64) * log2(e)
  const int ebase00 = 2047 - i0 - 15;

  // ---- carry init: T-tile c-range [0,16) of the first chunk tile ----
  float Bpc[4];
  {
    int er = ebase00 + jt0 * 64 + l15;
    er = er > 2047 ? 2047 : er;
    const bf16* erow = Eb + (size_t)er * 64 + quad * 8;
    bf16x8 e0 = *(const bf16x8*)erow;
    bf16x8 e1 = *(const bf16x8*)(erow + 32);
    f32x4 zz = (f32x4){0.f, 0.f, 0.f, 0.f};
    zz = MFMA16(aq0, e0, zz);
    zz = MFMA16(aq1, e1, zz);
#pragma unroll
    for (int r = 0; r < 4; r++)
      Bpc[r] = __int_as_float(__builtin_amdgcn_ds_bpermute(bpaddr[r], __float_as_int(zz[r])));
  }

  for (int jt = jt0; jt < jt1; jt++) {
    const int j0 = jt * 64;
    const bool diag = (jt == strip);  // only the last tile of A/B chunks
    // ---- E-band: fresh T-tiles nt=1..4 (nt=0 carried) ----
    float Bp[5][4];
#pragma unroll
    for (int r = 0; r < 4; r++) Bp[0][r] = Bpc[r];
    const int ebase = ebase00 + j0;
#pragma unroll
    for (int nt = 1; nt < 5; nt++) {
      int er = ebase + nt * 16 + l15;
      er = er > 2047 ? 2047 : er;  // clamped rows feed only masked entries
      const bf16* erow = Eb + (size_t)er * 64 + quad * 8;
      bf16x8 e0 = *(const bf16x8*)erow;
      bf16x8 e1 = *(const bf16x8*)(erow + 32);
      f32x4 zz = (f32x4){0.f, 0.f, 0.f, 0.f};
      zz = MFMA16(aq0, e0, zz);
      zz = MFMA16(aq1, e1, zz);
#pragma unroll
      for (int r = 0; r < 4; r++)
        Bp[nt][r] =
            __int_as_float(__builtin_amdgcn_ds_bpermute(bpaddr[r], __float_as_int(zz[r])));
    }
#pragma unroll
    for (int r = 0; r < 4; r++) Bpc[r] = Bp[4][r];

    // ---- S = q @ k^T, K fragments DIRECT from global (L2-resident) ----
    f32x4 s[4];
#pragma unroll
    for (int nt = 0; nt < 4; nt++) {
      int row = nt * 16 + l15;
      const bf16* krow = kh + (size_t)(j0 + row) * 64 + quad * 8;
      bf16x8 k0 = *(const bf16x8*)krow;
      bf16x8 k1 = *(const bf16x8*)(krow + 32);
      f32x4 zz = (f32x4){0.f, 0.f, 0.f, 0.f};
      zz = MFMA16(aq0, k0, zz);
      s[nt] = MFMA16(aq1, k1, zz);
    }
    // ---- logits: skew add + scale (+ mask on diag tile) + exp2 + P ----
    if (diag) {
#pragma unroll
      for (int nt = 0; nt < 4; nt++)
#pragma unroll
        for (int r = 0; r < 4; r++) {
          int u = quad * 4 + r;
          int j = nt * 16 + l15;
          float skew = loA[r] ? Bp[nt][r] : Bp[nt + 1][r];
          float logit = (s[nt][r] + skew) * sc;
          if (j0 + j > i0 + u) logit = -1e30f;  // causal; exp2 -> 0
          Pw[u * 72 + j] = (bf16)EXP2F(logit);
        }
    } else {
#pragma unroll
      for (int nt = 0; nt < 4; nt++)
#pragma unroll
        for (int r = 0; r < 4; r++) {
          int u = quad * 4 + r;
          int j = nt * 16 + l15;
          float skew = loA[r] ? Bp[nt][r] : Bp[nt + 1][r];
          Pw[u * 72 + j] = (bf16)EXP2F((s[nt][r] + skew) * sc);
        }
    }
    // ---- PV: O += P @ V ; Osum += P @ ones ; V DIRECT from global ----
    bf16x8 pa0 = *(const bf16x8*)&Pw[l15 * 72 + quad * 8];
    bf16x8 pa1 = *(const bf16x8*)&Pw[l15 * 72 + 32 + quad * 8];
    Osum = MFMA16(pa0, ones, Osum);
    Osum = MFMA16(pa1, ones, Osum);
#pragma unroll
    for (int nt = 0; nt < 4; nt++) {
      int row = nt * 16 + l15;
      const bf16* vrow = vh + (size_t)row * 2048 + j0 + quad * 8;
      bf16x8 v0 = *(const bf16x8*)vrow;
      bf16x8 v1 = *(const bf16x8*)(vrow + 32);
      O[nt] = MFMA16(pa0, v0, O[nt]);
      O[nt] = MFMA16(pa1, v1, O[nt]);
    }
  }
  // ---- epilogue: UNNORMALIZED partial O (bf16) + rowsum (f32) ----
  if (isB) {
    bf16* orow = Of1 + ((size_t)(bh * 1024 + (i0 - 1024))) * 64;
#pragma unroll
    for (int nt = 0; nt < 4; nt++)
#pragma unroll
      for (int r = 0; r < 4; r++)
        orow[(size_t)(quad * 4 + r) * 64 + nt * 16 + l15] = (bf16)O[nt][r];
    if (l15 == 0) {
#pragma unroll
      for (int r = 0; r < 4; r++) Os1[bh * 1024 + (i0 - 1024) + quad * 4 + r] = Osum[r];
    }
  } else {
    const int b = bh >> 3, hh = bh & 7;
    bf16* orow = attnb + ((size_t)(b * 2048 + i0)) * 512 + hh * 64;
#pragma unroll
    for (int nt = 0; nt < 4; nt++)
#pragma unroll
      for (int r = 0; r < 4; r++)
        orow[(size_t)(quad * 4 + r) * 512 + nt * 16 + l15] = (bf16)O[nt][r];
    if (l15 == 0) {
#pragma unroll
      for (int r = 0; r < 4; r++) Os0[bh * 2048 + i0 + quad * 4 + r] = Osum[r];
    }
  }
}

// ---------------------------------------------------------------------------
// normalize: attnb = (slot0 + slot1?) / (s0 + s1?), in place. vec8 per thread.
// ---------------------------------------------------------------------------
__global__ __launch_bounds__(256) void norm_kernel(bf16x8* __restrict__ attnb,
                                                   const bf16x8* __restrict__ Of1,
                                                   const float* __restrict__ Os0,
                                                   const float* __restrict__ Os1) {
  int i = blockIdx.x * 256 + threadIdx.x;  // vec8 index, 524288 total
  int col8 = i & 63;                       // 64 vec8 per row of 512
  int row = i >> 6;                        // b*2048 + l
  int b = row >> 11, l = row & 2047, h = col8 >> 3;
  int bh = b * 8 + h;
  float s = Os0[bh * 2048 + l];
  bf16x8 v0 = attnb[i];
  float acc[8];
#pragma unroll
  for (int j = 0; j < 8; j++) acc[j] = (float)v0[j];
  if (l >= 1024) {
    s += Os1[bh * 1024 + l - 1024];
    bf16x8 v1 = Of1[(size_t)(bh * 1024 + l - 1024) * 8 + (col8 & 7)];
#pragma unroll
    for (int j = 0; j < 8; j++) acc[j] += (float)v1[j];
  }
  float inv = 1.0f / s;
  bf16x8 o;
#pragma unroll
  for (int j = 0; j < 8; j++) o[j] = (bf16)(acc[j] * inv);
  attnb[i] = o;
}

// ---------------------------------------------------------------------------
extern "C" void kernel_launch(void* const* d_in, const int* in_sizes, int n_in,
                              void* d_out, int out_size, void* d_ws, size_t ws_size,
                              hipStream_t stream) {
  const float* Q = (const float*)d_in[0];
  const float* K = (const float*)d_in[1];
  const float* V = (const float*)d_in[2];
  const float* Wq = (const float*)d_in[4];
  const float* bq = (const float*)d_in[5];
  const float* Wk = (const float*)d_in[6];
  const float* bk = (const float*)d_in[7];
  const float* Wv = (const float*)d_in[8];
  const float* bv = (const float*)d_in[9];
  const float* fcw = (const float*)d_in[10];
  const float* fcb = (const float*)d_in[11];
  const float* E = (const float*)d_in[12];

  char* ws = (char*)d_ws;
  bf16* Xq = (bf16*)(ws + 0);
  bf16* Xk = (bf16*)(ws + 8388608);
  bf16* Xv = (bf16*)(ws + 16777216);
  bf16* Wqb = (bf16*)(ws + 25165824);
  bf16* Wkb = (bf16*)(ws + 25690112);
  bf16* Wvb = (bf16*)(ws + 26214400);
  bf16* fcwb = (bf16*)(ws + 26738688);
  bf16* Eb = (bf16*)(ws + 27262976);
  bf16* qbuf = (bf16*)(ws + 27525120);
  bf16* kbuf = (bf16*)(ws + 35913728);
  bf16* vTb = (bf16*)(ws + 44302336);   // old vbuf region: vT written directly
  bf16* Of1 = (bf16*)(ws + 52690944);   // 32*1024*64 bf16 = 4 MiB
  float* Os0 = (float*)(ws + 56885248); // 32*2048 f32 = 256 KiB
  float* Os1 = (float*)(ws + 57147392); // 32*1024 f32 = 128 KiB
  bf16* attnb = Xq;

  convert_all<<<13440, 256, 0, stream>>>(
      (const float4*)Q, (const float4*)K, (const float4*)V, (const float4*)Wq,
      (const float4*)Wk, (const float4*)Wv, (const float4*)fcw, (const float4*)E,
      (bf16x4*)Xq, (bf16x4*)Xk, (bf16x4*)Xv, (bf16x4*)Wqb, (bf16x4*)Wkb,
      (bf16x4*)Wvb, (bf16x4*)fcwb, (bf16x4*)Eb);

  proj_gemm<<<dim3(64, 4, 3), 256, 0, stream>>>(Xq, Xk, Xv, Wqb, Wkb, Wvb, bq, bk, bv,
                                                qbuf, kbuf, vTb);

  attn_kernel<<<1536, 256, 0, stream>>>(qbuf, kbuf, vTb, Eb, attnb, Of1, Os0, Os1);

  norm_kernel<<<2048, 256, 0, stream>>>((bf16x8*)attnb, (const bf16x8*)Of1, Os0, Os1);

  final_gemm<<<dim3(64, 4, 1), 256, 0, stream>>>(attnb, fcwb, fcb, (float*)d_out);
}

// Round 7
// 361.945 us; speedup vs baseline: 1.2140x; 1.2140x over previous
//
#include <hip/hip_runtime.h>
#include <stdint.h>

typedef __bf16 bf16;
typedef float f32x4 __attribute__((ext_vector_type(4)));
typedef bf16 bf16x8 __attribute__((ext_vector_type(8)));
typedef bf16 bf16x4 __attribute__((ext_vector_type(4)));

#define MFMA16(a, b, c) __builtin_amdgcn_mfma_f32_16x16x32_bf16((a), (b), (c), 0, 0, 0)
#define EXP2F(x) __builtin_amdgcn_exp2f(x)

__device__ __forceinline__ void gll16(const void* g, void* l) {
  __builtin_amdgcn_global_load_lds((const __attribute__((address_space(1))) void*)g,
                                   (__attribute__((address_space(3))) void*)l, 16, 0, 0);
}

// ---------------------------------------------------------------------------
// fp32 -> bf16 conversion of all tensors, one launch.
// ---------------------------------------------------------------------------
__global__ __launch_bounds__(256) void convert_all(
    const float4* __restrict__ Q, const float4* __restrict__ K, const float4* __restrict__ V,
    const float4* __restrict__ Wq, const float4* __restrict__ Wk, const float4* __restrict__ Wv,
    const float4* __restrict__ fcw, const float4* __restrict__ E,
    bf16x4* __restrict__ Xq, bf16x4* __restrict__ Xk, bf16x4* __restrict__ Xv,
    bf16x4* __restrict__ Wqb, bf16x4* __restrict__ Wkb, bf16x4* __restrict__ Wvb,
    bf16x4* __restrict__ fcb, bf16x4* __restrict__ Eb) {
  int i = blockIdx.x * 256 + threadIdx.x;
  const float4* s;
  bf16x4* d;
  int off;
  if (i < 1048576) { s = Q; d = Xq; off = i; }
  else if (i < 2097152) { s = K; d = Xk; off = i - 1048576; }
  else if (i < 3145728) { s = V; d = Xv; off = i - 2097152; }
  else if (i < 3211264) { s = Wq; d = Wqb; off = i - 3145728; }
  else if (i < 3276800) { s = Wk; d = Wkb; off = i - 3211264; }
  else if (i < 3342336) { s = Wv; d = Wvb; off = i - 3276800; }
  else if (i < 3407872) { s = fcw; d = fcb; off = i - 3342336; }
  else { s = E; d = Eb; off = i - 3407872; }
  float4 v = s[off];
  bf16x4 o;
  o[0] = (bf16)v.x; o[1] = (bf16)v.y; o[2] = (bf16)v.z; o[3] = (bf16)v.w;
  d[off] = o;
}

// ---------------------------------------------------------------------------
// GEMM core: C[128x128] = A[128x512] * Bt[128x512]^T (row-major bf16).
// ---------------------------------------------------------------------------
__device__ __forceinline__ void gemm_core(const bf16* __restrict__ A, const bf16* __restrict__ Bt,
                                          bf16* ldsA, bf16* ldsB, int m0, int n0,
                                          f32x4 acc[4][4]) {
  const int t = threadIdx.x;
  const int lane = t & 63, w = t >> 6;
  const int l15 = lane & 15, quad = lane >> 4;
  const int wm = w >> 1, wn = w & 1;
#pragma unroll
  for (int i = 0; i < 4; i++)
#pragma unroll
    for (int j = 0; j < 4; j++) acc[i][j] = (f32x4){0.f, 0.f, 0.f, 0.f};

  const int ch0 = t, ch1 = t + 256;
  const int r0 = ch0 >> 2, c0 = (ch0 & 3) ^ (r0 & 3);
  const int r1 = ch1 >> 2, c1 = (ch1 & 3) ^ (r1 & 3);

  int aoff[4], boff[4];
#pragma unroll
  for (int mt = 0; mt < 4; mt++) {
    int m = wm * 64 + mt * 16 + l15;
    aoff[mt] = (m << 6) + ((quad ^ (l15 & 3)) << 4);
    int n = wn * 64 + mt * 16 + l15;
    boff[mt] = (n << 6) + ((quad ^ (l15 & 3)) << 4);
  }
  bf16* ldsA1 = ldsA + w * 512;
  bf16* ldsA2 = ldsA + 2048 + w * 512;
  bf16* ldsB1 = ldsB + w * 512;
  bf16* ldsB2 = ldsB + 2048 + w * 512;

  for (int kt = 0; kt < 512; kt += 32) {
    gll16(A + (size_t)(m0 + r0) * 512 + kt + c0 * 8, ldsA1);
    gll16(A + (size_t)(m0 + r1) * 512 + kt + c1 * 8, ldsA2);
    gll16(Bt + (size_t)(n0 + r0) * 512 + kt + c0 * 8, ldsB1);
    gll16(Bt + (size_t)(n0 + r1) * 512 + kt + c1 * 8, ldsB2);
    __syncthreads();
    bf16x8 af[4], bfr[4];
#pragma unroll
    for (int mt = 0; mt < 4; mt++) af[mt] = *(const bf16x8*)((const char*)ldsA + aoff[mt]);
#pragma unroll
    for (int nt = 0; nt < 4; nt++) bfr[nt] = *(const bf16x8*)((const char*)ldsB + boff[nt]);
#pragma unroll
    for (int mt = 0; mt < 4; mt++)
#pragma unroll
      for (int nt = 0; nt < 4; nt++)
        acc[mt][nt] = MFMA16(af[mt], bfr[nt], acc[mt][nt]);
    __syncthreads();
  }
}

// proj_gemm: z==0/1 write q/k in (B,H,L,64). z==2 writes v DIRECTLY TRANSPOSED
// into vT (B,H,64,L) via an LDS-staged transpose (two 64-col halves reusing
// the 17.4KB smem), with fully coalesced bf16x8 stores along l.
__global__ __launch_bounds__(256) void proj_gemm(
    const bf16* __restrict__ Xq, const bf16* __restrict__ Xk, const bf16* __restrict__ Xv,
    const bf16* __restrict__ Wq, const bf16* __restrict__ Wk, const bf16* __restrict__ Wv,
    const float* __restrict__ bq, const float* __restrict__ bk, const float* __restrict__ bv,
    bf16* __restrict__ qb, bf16* __restrict__ kb, bf16* __restrict__ vT) {
  __shared__ __align__(16) char smem[17408];  // gemm: 2x8KB; transpose: 64x136 bf16
  bf16* ldsA = (bf16*)smem;
  bf16* ldsB = (bf16*)(smem + 8192);
  const int z = blockIdx.z;
  const bf16* A = z == 0 ? Xq : (z == 1 ? Xk : Xv);
  const bf16* W = z == 0 ? Wq : (z == 1 ? Wk : Wv);
  const float* bias = z == 0 ? bq : (z == 1 ? bk : bv);
  const int m0 = blockIdx.x * 128, n0 = blockIdx.y * 128;
  f32x4 acc[4][4];
  gemm_core(A, W, ldsA, ldsB, m0, n0, acc);

  const int t = threadIdx.x;
  const int lane = t & 63, w = t >> 6;
  const int l15 = lane & 15, quad = lane >> 4;
  const int wm = w >> 1, wn = w & 1;
  if (z == 2) {
    // ---- transposed epilogue: two halves over n (64 cols = one head each) --
    bf16* T = (bf16*)smem;  // [64][136]
    const int b = m0 >> 11, l0 = m0 & 2047, h0 = n0 >> 6;
#pragma unroll
    for (int half = 0; half < 2; half++) {
      __syncthreads();  // prev half's readers done / gemm LDS free
      if (wn == half) {
#pragma unroll
        for (int mt = 0; mt < 4; mt++)
#pragma unroll
          for (int nt = 0; nt < 4; nt++) {
            int n_loc = nt * 16 + l15;  // = d
            int mch = wm * 64 + mt * 16 + quad * 4;
            float bi = bias[n0 + half * 64 + n_loc];
            bf16x4 pv;
#pragma unroll
            for (int r = 0; r < 4; r++) pv[r] = (bf16)(acc[mt][nt][r] + bi);
            *(bf16x4*)&T[n_loc * 136 + mch] = pv;
          }
      }
      __syncthreads();
      bf16* dsth = vT + ((size_t)((b * 8 + h0 + half) * 64)) * 2048 + l0;
#pragma unroll
      for (int p = 0; p < 4; p++) {
        int id = t + 256 * p;      // 1024 chunks: 64 d-rows x 16 l-chunks
        int d = id >> 4, c = id & 15;
        bf16x8 v = *(const bf16x8*)&T[d * 136 + c * 8];
        *(bf16x8*)&dsth[(size_t)d * 2048 + c * 8] = v;
      }
    }
  } else {
    bf16* out = z == 0 ? qb : kb;
#pragma unroll
    for (int mt = 0; mt < 4; mt++)
#pragma unroll
      for (int nt = 0; nt < 4; nt++)
#pragma unroll
        for (int r = 0; r < 4; r++) {
          int gm = m0 + wm * 64 + mt * 16 + quad * 4 + r;
          int gn = n0 + wn * 64 + nt * 16 + l15;
          float v = acc[mt][nt][r] + bias[gn];
          int b = gm >> 11, l = gm & 2047, h = gn >> 6, d = gn & 63;
          out[(((size_t)(b * 8 + h)) * 2048 + l) * 64 + d] = (bf16)v;
        }
  }
}

__global__ __launch_bounds__(256) void final_gemm(const bf16* __restrict__ A,
                                                  const bf16* __restrict__ W,
                                                  const float* __restrict__ bias,
                                                  float* __restrict__ out) {
  __shared__ bf16 ldsA[128 * 32];
  __shared__ bf16 ldsB[128 * 32];
  const int m0 = blockIdx.x * 128, n0 = blockIdx.y * 128;
  f32x4 acc[4][4];
  gemm_core(A, W, ldsA, ldsB, m0, n0, acc);

  const int t = threadIdx.x;
  const int lane = t & 63, w = t >> 6;
  const int l15 = lane & 15, quad = lane >> 4;
  const int wm = w >> 1, wn = w & 1;
#pragma unroll
  for (int mt = 0; mt < 4; mt++)
#pragma unroll
    for (int nt = 0; nt < 4; nt++)
#pragma unroll
      for (int r = 0; r < 4; r++) {
        int gm = m0 + wm * 64 + mt * 16 + quad * 4 + r;
        int gn = n0 + wn * 64 + nt * 16 + l15;
        out[(size_t)gm * 512 + gn] = acc[mt][nt][r] + bias[gn];
      }
}

// ---------------------------------------------------------------------------
// Flash attention + relative position, causal. R7 = R6's BARRIER-FREE tile
// loop (K/V direct from L2-resident global; P in per-wave-private LDS; zero
// __syncthreads in the loop) with the launch bound relaxed to (256,4):
// VGPR cap 128 so the R0 register set (64 arch + ~24 acc) fits WITHOUT the
// scratch spill that destroyed R6 (VGPR=32, 640MB spill traffic/dispatch).
// LDS 9.2KB; occupancy now VGPR-limited (~5-6 blocks/CU), waves free-run.
// Jobs (48 per bh, grid 1536, all <=16 tiles, LPT order) unchanged.
// ---------------------------------------------------------------------------
__global__ __launch_bounds__(256, 4) void attn_kernel(
    const bf16* __restrict__ qbuf, const bf16* __restrict__ kbuf,
    const bf16* __restrict__ vT, const bf16* __restrict__ Eb,
    bf16* __restrict__ attnb, bf16* __restrict__ Of1,
    float* __restrict__ Os0, float* __restrict__ Os1) {
  __shared__ bf16 Pl[4][16 * 72];
  const int t = threadIdx.x, w = t >> 6, lane = t & 63;
  const int l15 = lane & 15, quad = lane >> 4;
  const int x = blockIdx.x;
  const int bh = x & 31, job = x >> 5;
  int strip, jt0, jt1;
  bool isB;
  if (job < 16) {
    strip = 16 + job; jt0 = 0; jt1 = 16; isB = false;
  } else {
    int k = job - 16, i = k >> 1;
    if ((k & 1) == 0) { strip = 15 - i; jt0 = 0; jt1 = 16 - i; isB = false; }
    else { strip = 31 - i; jt0 = 16; jt1 = 32 - i; isB = true; }
  }
  const int i0 = strip * 64 + w * 16;  // this wave's 16 q-rows
  bf16* Pw = Pl[w];
  const bf16* qh = qbuf + (size_t)bh * 2048 * 64;
  const bf16* kh = kbuf + (size_t)bh * 2048 * 64;
  const bf16* vh = vT + (size_t)bh * 64 * 2048;

  // bpermute lane addresses + tile-select mask, per acc register r
  int bpaddr[4];
  bool loA[4];
#pragma unroll
  for (int r = 0; r < 4; r++) {
    int u = quad * 4 + r;
    bpaddr[r] = (((l15 + 15 - u) & 15) + 16 * quad) * 4;
    loA[r] = (l15 <= u);  // source tile nt (else nt+1)
  }

  bf16x8 aq0, aq1;
  {
    const bf16* qrow = qh + (size_t)(i0 + l15) * 64 + quad * 8;
    aq0 = *(const bf16x8*)qrow;
    aq1 = *(const bf16x8*)(qrow + 32);
  }
  bf16x8 ones;
#pragma unroll
  for (int j = 0; j < 8; j++) ones[j] = (bf16)1.0f;

  f32x4 O[4], Osum;
  Osum = (f32x4){0.f, 0.f, 0.f, 0.f};
#pragma unroll
  for (int i = 0; i < 4; i++) O[i] = (f32x4){0.f, 0.f, 0.f, 0.f};
  const float sc = 0.125f * 1.44269504088896f;  // 1/sqrt(64) * log2(e)
  const int ebase00 = 2047 - i0 - 15;

  // ---- carry init: T-tile c-range [0,16) of the first chunk tile ----
  float Bpc[4];
  {
    int er = ebase00 + jt0 * 64 + l15;
    er = er > 2047 ? 2047 : er;
    const bf16* erow = Eb + (size_t)er * 64 + quad * 8;
    bf16x8 e0 = *(const bf16x8*)erow;
    bf16x8 e1 = *(const bf16x8*)(erow + 32);
    f32x4 zz = (f32x4){0.f, 0.f, 0.f, 0.f};
    zz = MFMA16(aq0, e0, zz);
    zz = MFMA16(aq1, e1, zz);
#pragma unroll
    for (int r = 0; r < 4; r++)
      Bpc[r] = __int_as_float(__builtin_amdgcn_ds_bpermute(bpaddr[r], __float_as_int(zz[r])));
  }

  for (int jt = jt0; jt < jt1; jt++) {
    const int j0 = jt * 64;
    const bool diag = (jt == strip);  // only the last tile of A/B chunks
    // ---- E-band: fresh T-tiles nt=1..4 (nt=0 carried) ----
    float Bp[5][4];
#pragma unroll
    for (int r = 0; r < 4; r++) Bp[0][r] = Bpc[r];
    const int ebase = ebase00 + j0;
#pragma unroll
    for (int nt = 1; nt < 5; nt++) {
      int er = ebase + nt * 16 + l15;
      er = er > 2047 ? 2047 : er;  // clamped rows feed only masked entries
      const bf16* erow = Eb + (size_t)er * 64 + quad * 8;
      bf16x8 e0 = *(const bf16x8*)erow;
      bf16x8 e1 = *(const bf16x8*)(erow + 32);
      f32x4 zz = (f32x4){0.f, 0.f, 0.f, 0.f};
      zz = MFMA16(aq0, e0, zz);
      zz = MFMA16(aq1, e1, zz);
#pragma unroll
      for (int r = 0; r < 4; r++)
        Bp[nt][r] =
            __int_as_float(__builtin_amdgcn_ds_bpermute(bpaddr[r], __float_as_int(zz[r])));
    }
#pragma unroll
    for (int r = 0; r < 4; r++) Bpc[r] = Bp[4][r];

    // ---- S = q @ k^T, K fragments DIRECT from global (L2-resident) ----
    f32x4 s[4];
#pragma unroll
    for (int nt = 0; nt < 4; nt++) {
      int row = nt * 16 + l15;
      const bf16* krow = kh + (size_t)(j0 + row) * 64 + quad * 8;
      bf16x8 k0 = *(const bf16x8*)krow;
      bf16x8 k1 = *(const bf16x8*)(krow + 32);
      f32x4 zz = (f32x4){0.f, 0.f, 0.f, 0.f};
      zz = MFMA16(aq0, k0, zz);
      s[nt] = MFMA16(aq1, k1, zz);
    }
    // ---- logits: skew add + scale (+ mask on diag tile) + exp2 + P ----
    if (diag) {
#pragma unroll
      for (int nt = 0; nt < 4; nt++)
#pragma unroll
        for (int r = 0; r < 4; r++) {
          int u = quad * 4 + r;
          int j = nt * 16 + l15;
          float skew = loA[r] ? Bp[nt][r] : Bp[nt + 1][r];
          float logit = (s[nt][r] + skew) * sc;
          if (j0 + j > i0 + u) logit = -1e30f;  // causal; exp2 -> 0
          Pw[u * 72 + j] = (bf16)EXP2F(logit);
        }
    } else {
#pragma unroll
      for (int nt = 0; nt < 4; nt++)
#pragma unroll
        for (int r = 0; r < 4; r++) {
          int u = quad * 4 + r;
          int j = nt * 16 + l15;
          float skew = loA[r] ? Bp[nt][r] : Bp[nt + 1][r];
          Pw[u * 72 + j] = (bf16)EXP2F((s[nt][r] + skew) * sc);
        }
    }
    // ---- PV: O += P @ V ; Osum += P @ ones ; V DIRECT from global ----
    bf16x8 pa0 = *(const bf16x8*)&Pw[l15 * 72 + quad * 8];
    bf16x8 pa1 = *(const bf16x8*)&Pw[l15 * 72 + 32 + quad * 8];
    Osum = MFMA16(pa0, ones, Osum);
    Osum = MFMA16(pa1, ones, Osum);
#pragma unroll
    for (int nt = 0; nt < 4; nt++) {
      int row = nt * 16 + l15;
      const bf16* vrow = vh + (size_t)row * 2048 + j0 + quad * 8;
      bf16x8 v0 = *(const bf16x8*)vrow;
      bf16x8 v1 = *(const bf16x8*)(vrow + 32);
      O[nt] = MFMA16(pa0, v0, O[nt]);
      O[nt] = MFMA16(pa1, v1, O[nt]);
    }
  }
  // ---- epilogue: UNNORMALIZED partial O (bf16) + rowsum (f32) ----
  if (isB) {
    bf16* orow = Of1 + ((size_t)(bh * 1024 + (i0 - 1024))) * 64;
#pragma unroll
    for (int nt = 0; nt < 4; nt++)
#pragma unroll
      for (int r = 0; r < 4; r++)
        orow[(size_t)(quad * 4 + r) * 64 + nt * 16 + l15] = (bf16)O[nt][r];
    if (l15 == 0) {
#pragma unroll
      for (int r = 0; r < 4; r++) Os1[bh * 1024 + (i0 - 1024) + quad * 4 + r] = Osum[r];
    }
  } else {
    const int b = bh >> 3, hh = bh & 7;
    bf16* orow = attnb + ((size_t)(b * 2048 + i0)) * 512 + hh * 64;
#pragma unroll
    for (int nt = 0; nt < 4; nt++)
#pragma unroll
      for (int r = 0; r < 4; r++)
        orow[(size_t)(quad * 4 + r) * 512 + nt * 16 + l15] = (bf16)O[nt][r];
    if (l15 == 0) {
#pragma unroll
      for (int r = 0; r < 4; r++) Os0[bh * 2048 + i0 + quad * 4 + r] = Osum[r];
    }
  }
}

// ---------------------------------------------------------------------------
// normalize: attnb = (slot0 + slot1?) / (s0 + s1?), in place. vec8 per thread.
// ---------------------------------------------------------------------------
__global__ __launch_bounds__(256) void norm_kernel(bf16x8* __restrict__ attnb,
                                                   const bf16x8* __restrict__ Of1,
                                                   const float* __restrict__ Os0,
                                                   const float* __restrict__ Os1) {
  int i = blockIdx.x * 256 + threadIdx.x;  // vec8 index, 524288 total
  int col8 = i & 63;                       // 64 vec8 per row of 512
  int row = i >> 6;                        // b*2048 + l
  int b = row >> 11, l = row & 2047, h = col8 >> 3;
  int bh = b * 8 + h;
  float s = Os0[bh * 2048 + l];
  bf16x8 v0 = attnb[i];
  float acc[8];
#pragma unroll
  for (int j = 0; j < 8; j++) acc[j] = (float)v0[j];
  if (l >= 1024) {
    s += Os1[bh * 1024 + l - 1024];
    bf16x8 v1 = Of1[(size_t)(bh * 1024 + l - 1024) * 8 + (col8 & 7)];
#pragma unroll
    for (int j = 0; j < 8; j++) acc[j] += (float)v1[j];
  }
  float inv = 1.0f / s;
  bf16x8 o;
#pragma unroll
  for (int j = 0; j < 8; j++) o[j] = (bf16)(acc[j] * inv);
  attnb[i] = o;
}

// ---------------------------------------------------------------------------
extern "C" void kernel_launch(void* const* d_in, const int* in_sizes, int n_in,
                              void* d_out, int out_size, void* d_ws, size_t ws_size,
                              hipStream_t stream) {
  const float* Q = (const float*)d_in[0];
  const float* K = (const float*)d_in[1];
  const float* V = (const float*)d_in[2];
  const float* Wq = (const float*)d_in[4];
  const float* bq = (const float*)d_in[5];
  const float* Wk = (const float*)d_in[6];
  const float* bk = (const float*)d_in[7];
  const float* Wv = (const float*)d_in[8];
  const float* bv = (const float*)d_in[9];
  const float* fcw = (const float*)d_in[10];
  const float* fcb = (const float*)d_in[11];
  const float* E = (const float*)d_in[12];

  char* ws = (char*)d_ws;
  bf16* Xq = (bf16*)(ws + 0);
  bf16* Xk = (bf16*)(ws + 8388608);
  bf16* Xv = (bf16*)(ws + 16777216);
  bf16* Wqb = (bf16*)(ws + 25165824);
  bf16* Wkb = (bf16*)(ws + 25690112);
  bf16* Wvb = (bf16*)(ws + 26214400);
  bf16* fcwb = (bf16*)(ws + 26738688);
  bf16* Eb = (bf16*)(ws + 27262976);
  bf16* qbuf = (bf16*)(ws + 27525120);
  bf16* kbuf = (bf16*)(ws + 35913728);
  bf16* vTb = (bf16*)(ws + 44302336);   // old vbuf region: vT written directly
  bf16* Of1 = (bf16*)(ws + 52690944);   // 32*1024*64 bf16 = 4 MiB
  float* Os0 = (float*)(ws + 56885248); // 32*2048 f32 = 256 KiB
  float* Os1 = (float*)(ws + 57147392); // 32*1024 f32 = 128 KiB
  bf16* attnb = Xq;

  convert_all<<<13440, 256, 0, stream>>>(
      (const float4*)Q, (const float4*)K, (const float4*)V, (const float4*)Wq,
      (const float4*)Wk, (const float4*)Wv, (const float4*)fcw, (const float4*)E,
      (bf16x4*)Xq, (bf16x4*)Xk, (bf16x4*)Xv, (bf16x4*)Wqb, (bf16x4*)Wkb,
      (bf16x4*)Wvb, (bf16x4*)fcwb, (bf16x4*)Eb);

  proj_gemm<<<dim3(64, 4, 3), 256, 0, stream>>>(Xq, Xk, Xv, Wqb, Wkb, Wvb, bq, bk, bv,
                                                qbuf, kbuf, vTb);

  attn_kernel<<<1536, 256, 0, stream>>>(qbuf, kbuf, vTb, Eb, attnb, Of1, Os0, Os1);

  norm_kernel<<<2048, 256, 0, stream>>>((bf16x8*)attnb, (const bf16x8*)Of1, Os0, Os1);

  final_gemm<<<dim3(64, 4, 1), 256, 0, stream>>>(attnb, fcwb, fcb, (float*)d_out);
}

// Round 8
// 252.816 us; speedup vs baseline: 1.7380x; 1.4317x over previous
//
#include <hip/hip_runtime.h>
#include <stdint.h>

typedef __bf16 bf16;
typedef float f32x4 __attribute__((ext_vector_type(4)));
typedef bf16 bf16x8 __attribute__((ext_vector_type(8)));
typedef bf16 bf16x4 __attribute__((ext_vector_type(4)));

#define MFMA16(a, b, c) __builtin_amdgcn_mfma_f32_16x16x32_bf16((a), (b), (c), 0, 0, 0)
#define EXP2F(x) __builtin_amdgcn_exp2f(x)

__device__ __forceinline__ void gll16(const void* g, void* l) {
  __builtin_amdgcn_global_load_lds((const __attribute__((address_space(1))) void*)g,
                                   (__attribute__((address_space(3))) void*)l, 16, 0, 0);
}

// ---------------------------------------------------------------------------
// fp32 -> bf16 conversion of all tensors, one launch.
// ---------------------------------------------------------------------------
__global__ __launch_bounds__(256) void convert_all(
    const float4* __restrict__ Q, const float4* __restrict__ K, const float4* __restrict__ V,
    const float4* __restrict__ Wq, const float4* __restrict__ Wk, const float4* __restrict__ Wv,
    const float4* __restrict__ fcw, const float4* __restrict__ E,
    bf16x4* __restrict__ Xq, bf16x4* __restrict__ Xk, bf16x4* __restrict__ Xv,
    bf16x4* __restrict__ Wqb, bf16x4* __restrict__ Wkb, bf16x4* __restrict__ Wvb,
    bf16x4* __restrict__ fcb, bf16x4* __restrict__ Eb) {
  int i = blockIdx.x * 256 + threadIdx.x;
  const float4* s;
  bf16x4* d;
  int off;
  if (i < 1048576) { s = Q; d = Xq; off = i; }
  else if (i < 2097152) { s = K; d = Xk; off = i - 1048576; }
  else if (i < 3145728) { s = V; d = Xv; off = i - 2097152; }
  else if (i < 3211264) { s = Wq; d = Wqb; off = i - 3145728; }
  else if (i < 3276800) { s = Wk; d = Wkb; off = i - 3211264; }
  else if (i < 3342336) { s = Wv; d = Wvb; off = i - 3276800; }
  else if (i < 3407872) { s = fcw; d = fcb; off = i - 3342336; }
  else { s = E; d = Eb; off = i - 3407872; }
  float4 v = s[off];
  bf16x4 o;
  o[0] = (bf16)v.x; o[1] = (bf16)v.y; o[2] = (bf16)v.z; o[3] = (bf16)v.w;
  d[off] = o;
}

// ---------------------------------------------------------------------------
// GEMM core: C[128x128] = A[128x512] * Bt[128x512]^T (row-major bf16).
// ---------------------------------------------------------------------------
__device__ __forceinline__ void gemm_core(const bf16* __restrict__ A, const bf16* __restrict__ Bt,
                                          bf16* ldsA, bf16* ldsB, int m0, int n0,
                                          f32x4 acc[4][4]) {
  const int t = threadIdx.x;
  const int lane = t & 63, w = t >> 6;
  const int l15 = lane & 15, quad = lane >> 4;
  const int wm = w >> 1, wn = w & 1;
#pragma unroll
  for (int i = 0; i < 4; i++)
#pragma unroll
    for (int j = 0; j < 4; j++) acc[i][j] = (f32x4){0.f, 0.f, 0.f, 0.f};

  const int ch0 = t, ch1 = t + 256;
  const int r0 = ch0 >> 2, c0 = (ch0 & 3) ^ (r0 & 3);
  const int r1 = ch1 >> 2, c1 = (ch1 & 3) ^ (r1 & 3);

  int aoff[4], boff[4];
#pragma unroll
  for (int mt = 0; mt < 4; mt++) {
    int m = wm * 64 + mt * 16 + l15;
    aoff[mt] = (m << 6) + ((quad ^ (l15 & 3)) << 4);
    int n = wn * 64 + mt * 16 + l15;
    boff[mt] = (n << 6) + ((quad ^ (l15 & 3)) << 4);
  }
  bf16* ldsA1 = ldsA + w * 512;
  bf16* ldsA2 = ldsA + 2048 + w * 512;
  bf16* ldsB1 = ldsB + w * 512;
  bf16* ldsB2 = ldsB + 2048 + w * 512;

  for (int kt = 0; kt < 512; kt += 32) {
    gll16(A + (size_t)(m0 + r0) * 512 + kt + c0 * 8, ldsA1);
    gll16(A + (size_t)(m0 + r1) * 512 + kt + c1 * 8, ldsA2);
    gll16(Bt + (size_t)(n0 + r0) * 512 + kt + c0 * 8, ldsB1);
    gll16(Bt + (size_t)(n0 + r1) * 512 + kt + c1 * 8, ldsB2);
    __syncthreads();
    bf16x8 af[4], bfr[4];
#pragma unroll
    for (int mt = 0; mt < 4; mt++) af[mt] = *(const bf16x8*)((const char*)ldsA + aoff[mt]);
#pragma unroll
    for (int nt = 0; nt < 4; nt++) bfr[nt] = *(const bf16x8*)((const char*)ldsB + boff[nt]);
#pragma unroll
    for (int mt = 0; mt < 4; mt++)
#pragma unroll
      for (int nt = 0; nt < 4; nt++)
        acc[mt][nt] = MFMA16(af[mt], bfr[nt], acc[mt][nt]);
    __syncthreads();
  }
}

// proj_gemm: z==0/1 write q/k in (B,H,L,64). z==2 writes v DIRECTLY TRANSPOSED
// into vT (B,H,64,L) via an LDS-staged transpose (two 64-col halves reusing
// the 17.4KB smem), with fully coalesced bf16x8 stores along l.
__global__ __launch_bounds__(256) void proj_gemm(
    const bf16* __restrict__ Xq, const bf16* __restrict__ Xk, const bf16* __restrict__ Xv,
    const bf16* __restrict__ Wq, const bf16* __restrict__ Wk, const bf16* __restrict__ Wv,
    const float* __restrict__ bq, const float* __restrict__ bk, const float* __restrict__ bv,
    bf16* __restrict__ qb, bf16* __restrict__ kb, bf16* __restrict__ vT) {
  __shared__ __align__(16) char smem[17408];  // gemm: 2x8KB; transpose: 64x136 bf16
  bf16* ldsA = (bf16*)smem;
  bf16* ldsB = (bf16*)(smem + 8192);
  const int z = blockIdx.z;
  const bf16* A = z == 0 ? Xq : (z == 1 ? Xk : Xv);
  const bf16* W = z == 0 ? Wq : (z == 1 ? Wk : Wv);
  const float* bias = z == 0 ? bq : (z == 1 ? bk : bv);
  const int m0 = blockIdx.x * 128, n0 = blockIdx.y * 128;
  f32x4 acc[4][4];
  gemm_core(A, W, ldsA, ldsB, m0, n0, acc);

  const int t = threadIdx.x;
  const int lane = t & 63, w = t >> 6;
  const int l15 = lane & 15, quad = lane >> 4;
  const int wm = w >> 1, wn = w & 1;
  if (z == 2) {
    // ---- transposed epilogue: two halves over n (64 cols = one head each) --
    bf16* T = (bf16*)smem;  // [64][136]
    const int b = m0 >> 11, l0 = m0 & 2047, h0 = n0 >> 6;
#pragma unroll
    for (int half = 0; half < 2; half++) {
      __syncthreads();  // prev half's readers done / gemm LDS free
      if (wn == half) {
#pragma unroll
        for (int mt = 0; mt < 4; mt++)
#pragma unroll
          for (int nt = 0; nt < 4; nt++) {
            int n_loc = nt * 16 + l15;  // = d
            int mch = wm * 64 + mt * 16 + quad * 4;
            float bi = bias[n0 + half * 64 + n_loc];
            bf16x4 pv;
#pragma unroll
            for (int r = 0; r < 4; r++) pv[r] = (bf16)(acc[mt][nt][r] + bi);
            *(bf16x4*)&T[n_loc * 136 + mch] = pv;
          }
      }
      __syncthreads();
      bf16* dsth = vT + ((size_t)((b * 8 + h0 + half) * 64)) * 2048 + l0;
#pragma unroll
      for (int p = 0; p < 4; p++) {
        int id = t + 256 * p;      // 1024 chunks: 64 d-rows x 16 l-chunks
        int d = id >> 4, c = id & 15;
        bf16x8 v = *(const bf16x8*)&T[d * 136 + c * 8];
        *(bf16x8*)&dsth[(size_t)d * 2048 + c * 8] = v;
      }
    }
  } else {
    bf16* out = z == 0 ? qb : kb;
#pragma unroll
    for (int mt = 0; mt < 4; mt++)
#pragma unroll
      for (int nt = 0; nt < 4; nt++)
#pragma unroll
        for (int r = 0; r < 4; r++) {
          int gm = m0 + wm * 64 + mt * 16 + quad * 4 + r;
          int gn = n0 + wn * 64 + nt * 16 + l15;
          float v = acc[mt][nt][r] + bias[gn];
          int b = gm >> 11, l = gm & 2047, h = gn >> 6, d = gn & 63;
          out[(((size_t)(b * 8 + h)) * 2048 + l) * 64 + d] = (bf16)v;
        }
  }
}

// ---------------------------------------------------------------------------
// final_gemm with FUSED NORMALIZATION: A-staging loads unnormalized attnb
// (+ Of1 slot for rows l>=1024), merges and scales by 1/(Os0+Os1) in f32,
// converts to bf16 and ds_writes to the EXACT byte layout the A-side gll16
// produced (dest byte = t*16 / 4096+t*16), so fragment reads are unchanged.
// Replaces the separate norm_kernel (one fewer launch, -21MB HBM traffic).
// B-side (fc weights) stays gll16. All normalization branches block-uniform.
// ---------------------------------------------------------------------------
__global__ __launch_bounds__(256) void final_gemm(
    const bf16* __restrict__ A, const bf16* __restrict__ Of1,
    const float* __restrict__ Os0, const float* __restrict__ Os1,
    const bf16* __restrict__ W, const float* __restrict__ bias,
    float* __restrict__ out) {
  __shared__ bf16 ldsA[128 * 32];
  __shared__ bf16 ldsB[128 * 32];
  const int t = threadIdx.x;
  const int lane = t & 63, w = t >> 6;
  const int l15 = lane & 15, quad = lane >> 4;
  const int wm = w >> 1, wn = w & 1;
  const int m0 = blockIdx.x * 128, n0 = blockIdx.y * 128;
  f32x4 acc[4][4];
#pragma unroll
  for (int i = 0; i < 4; i++)
#pragma unroll
    for (int j = 0; j < 4; j++) acc[i][j] = (f32x4){0.f, 0.f, 0.f, 0.f};

  const int ch1 = t + 256;
  const int r0 = t >> 2, c0 = (t & 3) ^ (r0 & 3);
  const int r1 = ch1 >> 2, c1 = (ch1 & 3) ^ (r1 & 3);

  int aoff[4], boff[4];
#pragma unroll
  for (int mt = 0; mt < 4; mt++) {
    int m = wm * 64 + mt * 16 + l15;
    aoff[mt] = (m << 6) + ((quad ^ (l15 & 3)) << 4);
    int n = wn * 64 + mt * 16 + l15;
    boff[mt] = (n << 6) + ((quad ^ (l15 & 3)) << 4);
  }
  bf16* ldsB1 = ldsB + w * 512;
  bf16* ldsB2 = ldsB + 2048 + w * 512;

  const int bA = m0 >> 11;            // block-uniform batch
  const int lA0 = (m0 & 2047) + r0;   // this thread's two A rows
  const int lA1 = (m0 & 2047) + r1;
  const bool hiL = (m0 & 2047) >= 1024;  // block-uniform slot-1 flag

  for (int kt = 0; kt < 512; kt += 32) {
    gll16(W + (size_t)(n0 + r0) * 512 + kt + c0 * 8, ldsB1);
    gll16(W + (size_t)(n0 + r1) * 512 + kt + c1 * 8, ldsB2);
    // ---- A chunks: load, merge slot1, normalize, convert, ds_write ----
    const int bh8 = bA * 8 + (kt >> 6);  // head h = kt>>6, uniform per step
    bf16x8 a0 = *(const bf16x8*)&A[(size_t)(m0 + r0) * 512 + kt + c0 * 8];
    bf16x8 a1 = *(const bf16x8*)&A[(size_t)(m0 + r1) * 512 + kt + c1 * 8];
    float s0 = Os0[bh8 * 2048 + lA0];
    float s1 = Os0[bh8 * 2048 + lA1];
    float f0[8], f1[8];
#pragma unroll
    for (int j = 0; j < 8; j++) { f0[j] = (float)a0[j]; f1[j] = (float)a1[j]; }
    if (hiL) {
      s0 += Os1[bh8 * 1024 + lA0 - 1024];
      s1 += Os1[bh8 * 1024 + lA1 - 1024];
      bf16x8 o0 = *(const bf16x8*)&Of1[((size_t)(bh8 * 1024 + lA0 - 1024)) * 64 +
                                       (kt & 63) + c0 * 8];
      bf16x8 o1 = *(const bf16x8*)&Of1[((size_t)(bh8 * 1024 + lA1 - 1024)) * 64 +
                                       (kt & 63) + c1 * 8];
#pragma unroll
      for (int j = 0; j < 8; j++) { f0[j] += (float)o0[j]; f1[j] += (float)o1[j]; }
    }
    float iv0 = 1.0f / s0, iv1 = 1.0f / s1;
    bf16x8 w0, w1;
#pragma unroll
    for (int j = 0; j < 8; j++) {
      w0[j] = (bf16)(f0[j] * iv0);
      w1[j] = (bf16)(f1[j] * iv1);
    }
    *(bf16x8*)((char*)ldsA + t * 16) = w0;         // same byte slot gll16 used
    *(bf16x8*)((char*)ldsA + 4096 + t * 16) = w1;
    __syncthreads();
    bf16x8 af[4], bfr[4];
#pragma unroll
    for (int mt = 0; mt < 4; mt++) af[mt] = *(const bf16x8*)((const char*)ldsA + aoff[mt]);
#pragma unroll
    for (int nt = 0; nt < 4; nt++) bfr[nt] = *(const bf16x8*)((const char*)ldsB + boff[nt]);
#pragma unroll
    for (int mt = 0; mt < 4; mt++)
#pragma unroll
      for (int nt = 0; nt < 4; nt++)
        acc[mt][nt] = MFMA16(af[mt], bfr[nt], acc[mt][nt]);
    __syncthreads();
  }

#pragma unroll
  for (int mt = 0; mt < 4; mt++)
#pragma unroll
    for (int nt = 0; nt < 4; nt++)
#pragma unroll
      for (int r = 0; r < 4; r++) {
        int gm = m0 + wm * 64 + mt * 16 + quad * 4 + r;
        int gn = n0 + wn * 64 + nt * 16 + l15;
        out[(size_t)gm * 512 + gn] = acc[mt][nt][r] + bias[gn];
      }
}

// ---------------------------------------------------------------------------
// Flash attention + relative position, causal — exact R0 structure (90.7us):
// single 16KB K/V buffer, 2 barriers/tile, E-band MFMA between staging-issue
// and consuming barrier, skew via ds_bpermute crossbar, P via LDS round-trip,
// Osum via ones-MFMA. 25.6KB LDS + ~64 VGPR -> 6 blocks/CU.
// (R7 lesson: K/V LDS staging is the COALESCING transform — per-lane MFMA
// fragment loads from global are 16-way scattered; do not remove staging.)
// Jobs (48 per bh, grid 1536, all <=16 tiles, LPT order):
//   job 0..15 : strip 16+j, jt [0,16)      (no diagonal)   -> slot0
//   job 16+2i : strip 15-i, jt [0,16-i)    (full strip)    -> slot0
//   job 17+2i : strip 31-i, jt [16,32-i)   (diag chunk)    -> slot1
// ---------------------------------------------------------------------------
__global__ __launch_bounds__(256, 4) void attn_kernel(
    const bf16* __restrict__ qbuf, const bf16* __restrict__ kbuf,
    const bf16* __restrict__ vT, const bf16* __restrict__ Eb,
    bf16* __restrict__ attnb, bf16* __restrict__ Of1,
    float* __restrict__ Os0, float* __restrict__ Os1) {
  __shared__ bf16 Kl[64 * 64];
  __shared__ bf16 Vl[64 * 64];
  __shared__ bf16 Pl[4][16 * 72];
  const int t = threadIdx.x, w = t >> 6, lane = t & 63;
  const int l15 = lane & 15, quad = lane >> 4;
  const int x = blockIdx.x;
  const int bh = x & 31, job = x >> 5;
  int strip, jt0, jt1;
  bool isB;
  if (job < 16) {
    strip = 16 + job; jt0 = 0; jt1 = 16; isB = false;
  } else {
    int k = job - 16, i = k >> 1;
    if ((k & 1) == 0) { strip = 15 - i; jt0 = 0; jt1 = 16 - i; isB = false; }
    else { strip = 31 - i; jt0 = 16; jt1 = 32 - i; isB = true; }
  }
  const int i0 = strip * 64 + w * 16;  // this wave's 16 q-rows
  bf16* Pw = Pl[w];
  const bf16* qh = qbuf + (size_t)bh * 2048 * 64;
  const bf16* kh = kbuf + (size_t)bh * 2048 * 64;
  const bf16* vh = vT + (size_t)bh * 64 * 2048;

  // staging: slot s holds (row = s>>3, chunk = (s&7)^(row&7)); thread t does
  // slots t and t+256; wave-uniform LDS byte base + lane*16B.
  const int sr0 = t >> 3, sc0 = (t & 7) ^ (sr0 & 7);
  const int sr1 = sr0 + 32;
  const int wb0 = (t & 192) * 16;  // byte offset of this wave's slot group
  const int wb1 = 4096 + wb0;

  // bpermute lane addresses + tile-select mask, per acc register r
  int bpaddr[4];
  bool loA[4];
#pragma unroll
  for (int r = 0; r < 4; r++) {
    int u = quad * 4 + r;
    bpaddr[r] = (((l15 + 15 - u) & 15) + 16 * quad) * 4;
    loA[r] = (l15 <= u);  // source tile nt (else nt+1)
  }

  bf16x8 aq0, aq1;
  {
    const bf16* qrow = qh + (size_t)(i0 + l15) * 64 + quad * 8;
    aq0 = *(const bf16x8*)qrow;
    aq1 = *(const bf16x8*)(qrow + 32);
  }
  bf16x8 ones;
#pragma unroll
  for (int j = 0; j < 8; j++) ones[j] = (bf16)1.0f;

  f32x4 O[4], Osum;
  Osum = (f32x4){0.f, 0.f, 0.f, 0.f};
#pragma unroll
  for (int i = 0; i < 4; i++) O[i] = (f32x4){0.f, 0.f, 0.f, 0.f};
  const float sc = 0.125f * 1.44269504088896f;  // 1/sqrt(64) * log2(e)
  const int ebase00 = 2047 - i0 - 15;

  // ---- carry init: T-tile c-range [0,16) of the first chunk tile ----
  float Bpc[4];
  {
    int er = ebase00 + jt0 * 64 + l15;
    er = er > 2047 ? 2047 : er;
    const bf16* erow = Eb + (size_t)er * 64 + quad * 8;
    bf16x8 e0 = *(const bf16x8*)erow;
    bf16x8 e1 = *(const bf16x8*)(erow + 32);
    f32x4 zz = (f32x4){0.f, 0.f, 0.f, 0.f};
    zz = MFMA16(aq0, e0, zz);
    zz = MFMA16(aq1, e1, zz);
#pragma unroll
    for (int r = 0; r < 4; r++)
      Bpc[r] = __int_as_float(__builtin_amdgcn_ds_bpermute(bpaddr[r], __float_as_int(zz[r])));
  }

  for (int jt = jt0; jt < jt1; jt++) {
    const int j0 = jt * 64;
    const bool diag = (jt == strip);  // only the last tile of A/B chunks
    __syncthreads();  // all waves done reading K/V of previous tile
    // ---- issue staging for this tile (async into LDS) ----
    gll16(kh + (size_t)(j0 + sr0) * 64 + sc0 * 8, (char*)Kl + wb0);
    gll16(kh + (size_t)(j0 + sr1) * 64 + sc0 * 8, (char*)Kl + wb1);
    gll16(vh + (size_t)sr0 * 2048 + j0 + sc0 * 8, (char*)Vl + wb0);
    gll16(vh + (size_t)sr1 * 2048 + j0 + sc0 * 8, (char*)Vl + wb1);
    // ---- E-band: fresh T-tiles nt=1..4 (nt=0 carried); overlaps staging ----
    float Bp[5][4];
#pragma unroll
    for (int r = 0; r < 4; r++) Bp[0][r] = Bpc[r];
    const int ebase = ebase00 + j0;
#pragma unroll
    for (int nt = 1; nt < 5; nt++) {
      int er = ebase + nt * 16 + l15;
      er = er > 2047 ? 2047 : er;  // clamped rows feed only masked entries
      const bf16* erow = Eb + (size_t)er * 64 + quad * 8;
      bf16x8 e0 = *(const bf16x8*)erow;
      bf16x8 e1 = *(const bf16x8*)(erow + 32);
      f32x4 zz = (f32x4){0.f, 0.f, 0.f, 0.f};
      zz = MFMA16(aq0, e0, zz);
      zz = MFMA16(aq1, e1, zz);
#pragma unroll
      for (int r = 0; r < 4; r++)
        Bp[nt][r] =
            __int_as_float(__builtin_amdgcn_ds_bpermute(bpaddr[r], __float_as_int(zz[r])));
    }
#pragma unroll
    for (int r = 0; r < 4; r++) Bpc[r] = Bp[4][r];

    __syncthreads();  // staging complete (vmcnt drained before barrier)
    // ---- S = q @ k^T from LDS (swizzled b128 reads) ----
    f32x4 s[4];
#pragma unroll
    for (int nt = 0; nt < 4; nt++) {
      int row = nt * 16 + l15;
      bf16x8 k0 = *(const bf16x8*)(Kl + ((row << 3) + (quad ^ (row & 7))) * 8);
      bf16x8 k1 = *(const bf16x8*)(Kl + ((row << 3) + ((quad + 4) ^ (row & 7))) * 8);
      f32x4 zz = (f32x4){0.f, 0.f, 0.f, 0.f};
      zz = MFMA16(aq0, k0, zz);
      s[nt] = MFMA16(aq1, k1, zz);
    }
    // ---- logits: skew add + scale (+ mask on diag tile) + exp2 + P ----
    if (diag) {
#pragma unroll
      for (int nt = 0; nt < 4; nt++)
#pragma unroll
        for (int r = 0; r < 4; r++) {
          int u = quad * 4 + r;
          int j = nt * 16 + l15;
          float skew = loA[r] ? Bp[nt][r] : Bp[nt + 1][r];
          float logit = (s[nt][r] + skew) * sc;
          if (j0 + j > i0 + u) logit = -1e30f;  // causal; exp2 -> 0
          Pw[u * 72 + j] = (bf16)EXP2F(logit);
        }
    } else {
#pragma unroll
      for (int nt = 0; nt < 4; nt++)
#pragma unroll
        for (int r = 0; r < 4; r++) {
          int u = quad * 4 + r;
          int j = nt * 16 + l15;
          float skew = loA[r] ? Bp[nt][r] : Bp[nt + 1][r];
          Pw[u * 72 + j] = (bf16)EXP2F((s[nt][r] + skew) * sc);
        }
    }
    // ---- PV: O += P @ V ; Osum += P @ ones ----
    bf16x8 pa0 = *(const bf16x8*)&Pw[l15 * 72 + quad * 8];
    bf16x8 pa1 = *(const bf16x8*)&Pw[l15 * 72 + 32 + quad * 8];
    Osum = MFMA16(pa0, ones, Osum);
    Osum = MFMA16(pa1, ones, Osum);
#pragma unroll
    for (int nt = 0; nt < 4; nt++) {
      int row = nt * 16 + l15;
      bf16x8 v0 = *(const bf16x8*)(Vl + ((row << 3) + (quad ^ (row & 7))) * 8);
      bf16x8 v1 = *(const bf16x8*)(Vl + ((row << 3) + ((quad + 4) ^ (row & 7))) * 8);
      O[nt] = MFMA16(pa0, v0, O[nt]);
      O[nt] = MFMA16(pa1, v1, O[nt]);
    }
  }
  // ---- epilogue: UNNORMALIZED partial O (bf16) + rowsum (f32) ----
  if (isB) {
    bf16* orow = Of1 + ((size_t)(bh * 1024 + (i0 - 1024))) * 64;
#pragma unroll
    for (int nt = 0; nt < 4; nt++)
#pragma unroll
      for (int r = 0; r < 4; r++)
        orow[(size_t)(quad * 4 + r) * 64 + nt * 16 + l15] = (bf16)O[nt][r];
    if (l15 == 0) {
#pragma unroll
      for (int r = 0; r < 4; r++) Os1[bh * 1024 + (i0 - 1024) + quad * 4 + r] = Osum[r];
    }
  } else {
    const int b = bh >> 3, hh = bh & 7;
    bf16* orow = attnb + ((size_t)(b * 2048 + i0)) * 512 + hh * 64;
#pragma unroll
    for (int nt = 0; nt < 4; nt++)
#pragma unroll
      for (int r = 0; r < 4; r++)
        orow[(size_t)(quad * 4 + r) * 512 + nt * 16 + l15] = (bf16)O[nt][r];
    if (l15 == 0) {
#pragma unroll
      for (int r = 0; r < 4; r++) Os0[bh * 2048 + i0 + quad * 4 + r] = Osum[r];
    }
  }
}

// ---------------------------------------------------------------------------
extern "C" void kernel_launch(void* const* d_in, const int* in_sizes, int n_in,
                              void* d_out, int out_size, void* d_ws, size_t ws_size,
                              hipStream_t stream) {
  const float* Q = (const float*)d_in[0];
  const float* K = (const float*)d_in[1];
  const float* V = (const float*)d_in[2];
  const float* Wq = (const float*)d_in[4];
  const float* bq = (const float*)d_in[5];
  const float* Wk = (const float*)d_in[6];
  const float* bk = (const float*)d_in[7];
  const float* Wv = (const float*)d_in[8];
  const float* bv = (const float*)d_in[9];
  const float* fcw = (const float*)d_in[10];
  const float* fcb = (const float*)d_in[11];
  const float* E = (const float*)d_in[12];

  char* ws = (char*)d_ws;
  bf16* Xq = (bf16*)(ws + 0);
  bf16* Xk = (bf16*)(ws + 8388608);
  bf16* Xv = (bf16*)(ws + 16777216);
  bf16* Wqb = (bf16*)(ws + 25165824);
  bf16* Wkb = (bf16*)(ws + 25690112);
  bf16* Wvb = (bf16*)(ws + 26214400);
  bf16* fcwb = (bf16*)(ws + 26738688);
  bf16* Eb = (bf16*)(ws + 27262976);
  bf16* qbuf = (bf16*)(ws + 27525120);
  bf16* kbuf = (bf16*)(ws + 35913728);
  bf16* vTb = (bf16*)(ws + 44302336);   // old vbuf region: vT written directly
  bf16* Of1 = (bf16*)(ws + 52690944);   // 32*1024*64 bf16 = 4 MiB
  float* Os0 = (float*)(ws + 56885248); // 32*2048 f32 = 256 KiB
  float* Os1 = (float*)(ws + 57147392); // 32*1024 f32 = 128 KiB
  bf16* attnb = Xq;

  convert_all<<<13440, 256, 0, stream>>>(
      (const float4*)Q, (const float4*)K, (const float4*)V, (const float4*)Wq,
      (const float4*)Wk, (const float4*)Wv, (const float4*)fcw, (const float4*)E,
      (bf16x4*)Xq, (bf16x4*)Xk, (bf16x4*)Xv, (bf16x4*)Wqb, (bf16x4*)Wkb,
      (bf16x4*)Wvb, (bf16x4*)fcwb, (bf16x4*)Eb);

  proj_gemm<<<dim3(64, 4, 3), 256, 0, stream>>>(Xq, Xk, Xv, Wqb, Wkb, Wvb, bq, bk, bv,
                                                qbuf, kbuf, vTb);

  attn_kernel<<<1536, 256, 0, stream>>>(qbuf, kbuf, vTb, Eb, attnb, Of1, Os0, Os1);

  final_gemm<<<dim3(64, 4), 256, 0, stream>>>(attnb, Of1, Os0, Os1, fcwb, fcb,
                                              (float*)d_out);
}

// Round 9
// 244.073 us; speedup vs baseline: 1.8003x; 1.0358x over previous
//
#include <hip/hip_runtime.h>
#include <stdint.h>

typedef __bf16 bf16;
typedef float f32x4 __attribute__((ext_vector_type(4)));
typedef bf16 bf16x8 __attribute__((ext_vector_type(8)));
typedef bf16 bf16x4 __attribute__((ext_vector_type(4)));

#define MFMA16(a, b, c) __builtin_amdgcn_mfma_f32_16x16x32_bf16((a), (b), (c), 0, 0, 0)
#define EXP2F(x) __builtin_amdgcn_exp2f(x)

__device__ __forceinline__ void gll16(const void* g, void* l) {
  __builtin_amdgcn_global_load_lds((const __attribute__((address_space(1))) void*)g,
                                   (__attribute__((address_space(3))) void*)l, 16, 0, 0);
}

// ---------------------------------------------------------------------------
// fp32 -> bf16 conversion of all tensors, one launch.
// ---------------------------------------------------------------------------
__global__ __launch_bounds__(256) void convert_all(
    const float4* __restrict__ Q, const float4* __restrict__ K, const float4* __restrict__ V,
    const float4* __restrict__ Wq, const float4* __restrict__ Wk, const float4* __restrict__ Wv,
    const float4* __restrict__ fcw, const float4* __restrict__ E,
    bf16x4* __restrict__ Xq, bf16x4* __restrict__ Xk, bf16x4* __restrict__ Xv,
    bf16x4* __restrict__ Wqb, bf16x4* __restrict__ Wkb, bf16x4* __restrict__ Wvb,
    bf16x4* __restrict__ fcb, bf16x4* __restrict__ Eb) {
  int i = blockIdx.x * 256 + threadIdx.x;
  const float4* s;
  bf16x4* d;
  int off;
  if (i < 1048576) { s = Q; d = Xq; off = i; }
  else if (i < 2097152) { s = K; d = Xk; off = i - 1048576; }
  else if (i < 3145728) { s = V; d = Xv; off = i - 2097152; }
  else if (i < 3211264) { s = Wq; d = Wqb; off = i - 3145728; }
  else if (i < 3276800) { s = Wk; d = Wkb; off = i - 3211264; }
  else if (i < 3342336) { s = Wv; d = Wvb; off = i - 3276800; }
  else if (i < 3407872) { s = fcw; d = fcb; off = i - 3342336; }
  else { s = E; d = Eb; off = i - 3407872; }
  float4 v = s[off];
  bf16x4 o;
  o[0] = (bf16)v.x; o[1] = (bf16)v.y; o[2] = (bf16)v.z; o[3] = (bf16)v.w;
  d[off] = o;
}

// ---------------------------------------------------------------------------
// GEMM core, 128x64 tile: C[128x64] = A[128x512] * Bt[64x512]^T (bf16).
// BK=32 (proven staging pattern). Half-N tile doubles the grid so proj runs
// 6 blocks/CU and final 2 blocks/CU (was 3 and 1 — latency-starved).
// Wave layout: 2x2 waves, wave tile 64 rows x 32 cols, acc[4][2].
// ---------------------------------------------------------------------------
__device__ __forceinline__ void gemm_core64(const bf16* __restrict__ A,
                                            const bf16* __restrict__ Bt, bf16* ldsA,
                                            bf16* ldsB, int m0, int n0, f32x4 acc[4][2]) {
  const int t = threadIdx.x;
  const int lane = t & 63, w = t >> 6;
  const int l15 = lane & 15, quad = lane >> 4;
  const int wm = w >> 1, wn = w & 1;
#pragma unroll
  for (int i = 0; i < 4; i++)
#pragma unroll
    for (int j = 0; j < 2; j++) acc[i][j] = (f32x4){0.f, 0.f, 0.f, 0.f};

  // staging: slot s at byte s*16 holds (row = s>>2, chunk = (s&3)^(row&3)).
  // A: slots t (rows 0..63) and t+256 (rows 64..127); B: slots t (rows 0..63).
  const int r0 = t >> 2, c0 = (t & 3) ^ (r0 & 3);
  const int r1 = r0 + 64;  // (r1&3)==(r0&3) so chunk xor is c0 for both

  int aoff[4], boff[2];
#pragma unroll
  for (int mt = 0; mt < 4; mt++) {
    int m = wm * 64 + mt * 16 + l15;
    aoff[mt] = (m << 6) + ((quad ^ (l15 & 3)) << 4);
  }
#pragma unroll
  for (int nt = 0; nt < 2; nt++) {
    int n = wn * 32 + nt * 16 + l15;
    boff[nt] = (n << 6) + ((quad ^ (l15 & 3)) << 4);
  }
  bf16* ldsA1 = ldsA + w * 512;
  bf16* ldsA2 = ldsA + 2048 + w * 512;
  bf16* ldsB1 = ldsB + w * 512;

  for (int kt = 0; kt < 512; kt += 32) {
    gll16(A + (size_t)(m0 + r0) * 512 + kt + c0 * 8, ldsA1);
    gll16(A + (size_t)(m0 + r1) * 512 + kt + c0 * 8, ldsA2);
    gll16(Bt + (size_t)(n0 + r0) * 512 + kt + c0 * 8, ldsB1);
    __syncthreads();
    bf16x8 af[4], bfr[2];
#pragma unroll
    for (int mt = 0; mt < 4; mt++) af[mt] = *(const bf16x8*)((const char*)ldsA + aoff[mt]);
#pragma unroll
    for (int nt = 0; nt < 2; nt++) bfr[nt] = *(const bf16x8*)((const char*)ldsB + boff[nt]);
#pragma unroll
    for (int mt = 0; mt < 4; mt++)
#pragma unroll
      for (int nt = 0; nt < 2; nt++)
        acc[mt][nt] = MFMA16(af[mt], bfr[nt], acc[mt][nt]);
    __syncthreads();
  }
}

// proj_gemm: 128x64 tiles, grid (64, 8, 3) = 1536 blocks (6/CU).
// z==0/1 write q/k in (B,H,L,64). z==2 (one head per block) writes v DIRECTLY
// TRANSPOSED into vT (B,H,64,L) via LDS-staged transpose, coalesced stores.
__global__ __launch_bounds__(256) void proj_gemm(
    const bf16* __restrict__ Xq, const bf16* __restrict__ Xk, const bf16* __restrict__ Xv,
    const bf16* __restrict__ Wq, const bf16* __restrict__ Wk, const bf16* __restrict__ Wv,
    const float* __restrict__ bq, const float* __restrict__ bk, const float* __restrict__ bv,
    bf16* __restrict__ qb, bf16* __restrict__ kb, bf16* __restrict__ vT) {
  __shared__ __align__(16) char smem[17408];  // gemm: 8KB A + 4KB B; transpose: 64x136
  bf16* ldsA = (bf16*)smem;
  bf16* ldsB = (bf16*)(smem + 8192);
  const int z = blockIdx.z;
  const bf16* A = z == 0 ? Xq : (z == 1 ? Xk : Xv);
  const bf16* W = z == 0 ? Wq : (z == 1 ? Wk : Wv);
  const float* bias = z == 0 ? bq : (z == 1 ? bk : bv);
  const int m0 = blockIdx.x * 128, n0 = blockIdx.y * 64;
  f32x4 acc[4][2];
  gemm_core64(A, W, ldsA, ldsB, m0, n0, acc);

  const int t = threadIdx.x;
  const int lane = t & 63, w = t >> 6;
  const int l15 = lane & 15, quad = lane >> 4;
  const int wm = w >> 1, wn = w & 1;
  if (z == 2) {
    // ---- transposed epilogue: this block covers ONE head (64 d-cols) ----
    bf16* T = (bf16*)smem;  // [64][136]
    const int b = m0 >> 11, l0 = m0 & 2047, h0 = blockIdx.y;
    // gemm loop ended with __syncthreads -> smem free for reuse
#pragma unroll
    for (int mt = 0; mt < 4; mt++)
#pragma unroll
      for (int nt = 0; nt < 2; nt++) {
        int d = wn * 32 + nt * 16 + l15;
        int lloc = wm * 64 + mt * 16 + quad * 4;
        float bi = bias[n0 + d];
        bf16x4 pv;
#pragma unroll
        for (int r = 0; r < 4; r++) pv[r] = (bf16)(acc[mt][nt][r] + bi);
        *(bf16x4*)&T[d * 136 + lloc] = pv;
      }
    __syncthreads();
    bf16* dsth = vT + ((size_t)((b * 8 + h0) * 64)) * 2048 + l0;
#pragma unroll
    for (int p = 0; p < 4; p++) {
      int id = t + 256 * p;  // 1024 chunks: 64 d-rows x 16 l-chunks of 8
      int d = id >> 4, c = id & 15;
      bf16x8 v = *(const bf16x8*)&T[d * 136 + c * 8];
      *(bf16x8*)&dsth[(size_t)d * 2048 + c * 8] = v;
    }
  } else {
    bf16* out = z == 0 ? qb : kb;
#pragma unroll
    for (int mt = 0; mt < 4; mt++)
#pragma unroll
      for (int nt = 0; nt < 2; nt++)
#pragma unroll
        for (int r = 0; r < 4; r++) {
          int gm = m0 + wm * 64 + mt * 16 + quad * 4 + r;
          int gn = n0 + wn * 32 + nt * 16 + l15;
          float v = acc[mt][nt][r] + bias[gn];
          int b = gm >> 11, l = gm & 2047, h = gn >> 6, d = gn & 63;
          out[(((size_t)(b * 8 + h)) * 2048 + l) * 64 + d] = (bf16)v;
        }
  }
}

// final_gemm: 128x64 tiles, grid (64, 8) = 512 blocks (2/CU; was 1/CU).
__global__ __launch_bounds__(256) void final_gemm(const bf16* __restrict__ A,
                                                  const bf16* __restrict__ W,
                                                  const float* __restrict__ bias,
                                                  float* __restrict__ out) {
  __shared__ __align__(16) char smem[12288];
  bf16* ldsA = (bf16*)smem;
  bf16* ldsB = (bf16*)(smem + 8192);
  const int m0 = blockIdx.x * 128, n0 = blockIdx.y * 64;
  f32x4 acc[4][2];
  gemm_core64(A, W, ldsA, ldsB, m0, n0, acc);

  const int t = threadIdx.x;
  const int lane = t & 63, w = t >> 6;
  const int l15 = lane & 15, quad = lane >> 4;
  const int wm = w >> 1, wn = w & 1;
#pragma unroll
  for (int mt = 0; mt < 4; mt++)
#pragma unroll
    for (int nt = 0; nt < 2; nt++)
#pragma unroll
      for (int r = 0; r < 4; r++) {
        int gm = m0 + wm * 64 + mt * 16 + quad * 4 + r;
        int gn = n0 + wn * 32 + nt * 16 + l15;
        out[(size_t)gm * 512 + gn] = acc[mt][nt][r] + bias[gn];
      }
}

// ---------------------------------------------------------------------------
// Flash attention + relative position, causal — exact R5/R0 structure (~90us):
// single 16KB K/V buffer, 2 barriers/tile, E-band MFMA between staging-issue
// and consuming barrier, skew via ds_bpermute crossbar, P via LDS round-trip,
// Osum via ones-MFMA. 25.6KB LDS + ~64 VGPR -> 6 blocks/CU.
// (R7 lesson: K/V LDS staging is the COALESCING transform; R2/R6 lessons:
// occupancy > pipelining here; R1/R3: convoy is equilibrium, backfill null.)
// Jobs (48 per bh, grid 1536, all <=16 tiles, LPT order):
//   job 0..15 : strip 16+j, jt [0,16)      (no diagonal)   -> slot0
//   job 16+2i : strip 15-i, jt [0,16-i)    (full strip)    -> slot0
//   job 17+2i : strip 31-i, jt [16,32-i)   (diag chunk)    -> slot1
// ---------------------------------------------------------------------------
__global__ __launch_bounds__(256, 4) void attn_kernel(
    const bf16* __restrict__ qbuf, const bf16* __restrict__ kbuf,
    const bf16* __restrict__ vT, const bf16* __restrict__ Eb,
    bf16* __restrict__ attnb, bf16* __restrict__ Of1,
    float* __restrict__ Os0, float* __restrict__ Os1) {
  __shared__ bf16 Kl[64 * 64];
  __shared__ bf16 Vl[64 * 64];
  __shared__ bf16 Pl[4][16 * 72];
  const int t = threadIdx.x, w = t >> 6, lane = t & 63;
  const int l15 = lane & 15, quad = lane >> 4;
  const int x = blockIdx.x;
  const int bh = x & 31, job = x >> 5;
  int strip, jt0, jt1;
  bool isB;
  if (job < 16) {
    strip = 16 + job; jt0 = 0; jt1 = 16; isB = false;
  } else {
    int k = job - 16, i = k >> 1;
    if ((k & 1) == 0) { strip = 15 - i; jt0 = 0; jt1 = 16 - i; isB = false; }
    else { strip = 31 - i; jt0 = 16; jt1 = 32 - i; isB = true; }
  }
  const int i0 = strip * 64 + w * 16;  // this wave's 16 q-rows
  bf16* Pw = Pl[w];
  const bf16* qh = qbuf + (size_t)bh * 2048 * 64;
  const bf16* kh = kbuf + (size_t)bh * 2048 * 64;
  const bf16* vh = vT + (size_t)bh * 64 * 2048;

  // staging: slot s holds (row = s>>3, chunk = (s&7)^(row&7)); thread t does
  // slots t and t+256; wave-uniform LDS byte base + lane*16B.
  const int sr0 = t >> 3, sc0 = (t & 7) ^ (sr0 & 7);
  const int sr1 = sr0 + 32;
  const int wb0 = (t & 192) * 16;  // byte offset of this wave's slot group
  const int wb1 = 4096 + wb0;

  // bpermute lane addresses + tile-select mask, per acc register r
  int bpaddr[4];
  bool loA[4];
#pragma unroll
  for (int r = 0; r < 4; r++) {
    int u = quad * 4 + r;
    bpaddr[r] = (((l15 + 15 - u) & 15) + 16 * quad) * 4;
    loA[r] = (l15 <= u);  // source tile nt (else nt+1)
  }

  bf16x8 aq0, aq1;
  {
    const bf16* qrow = qh + (size_t)(i0 + l15) * 64 + quad * 8;
    aq0 = *(const bf16x8*)qrow;
    aq1 = *(const bf16x8*)(qrow + 32);
  }
  bf16x8 ones;
#pragma unroll
  for (int j = 0; j < 8; j++) ones[j] = (bf16)1.0f;

  f32x4 O[4], Osum;
  Osum = (f32x4){0.f, 0.f, 0.f, 0.f};
#pragma unroll
  for (int i = 0; i < 4; i++) O[i] = (f32x4){0.f, 0.f, 0.f, 0.f};
  const float sc = 0.125f * 1.44269504088896f;  // 1/sqrt(64) * log2(e)
  const int ebase00 = 2047 - i0 - 15;

  // ---- carry init: T-tile c-range [0,16) of the first chunk tile ----
  float Bpc[4];
  {
    int er = ebase00 + jt0 * 64 + l15;
    er = er > 2047 ? 2047 : er;
    const bf16* erow = Eb + (size_t)er * 64 + quad * 8;
    bf16x8 e0 = *(const bf16x8*)erow;
    bf16x8 e1 = *(const bf16x8*)(erow + 32);
    f32x4 zz = (f32x4){0.f, 0.f, 0.f, 0.f};
    zz = MFMA16(aq0, e0, zz);
    zz = MFMA16(aq1, e1, zz);
#pragma unroll
    for (int r = 0; r < 4; r++)
      Bpc[r] = __int_as_float(__builtin_amdgcn_ds_bpermute(bpaddr[r], __float_as_int(zz[r])));
  }

  for (int jt = jt0; jt < jt1; jt++) {
    const int j0 = jt * 64;
    const bool diag = (jt == strip);  // only the last tile of A/B chunks
    __syncthreads();  // all waves done reading K/V of previous tile
    // ---- issue staging for this tile (async into LDS) ----
    gll16(kh + (size_t)(j0 + sr0) * 64 + sc0 * 8, (char*)Kl + wb0);
    gll16(kh + (size_t)(j0 + sr1) * 64 + sc0 * 8, (char*)Kl + wb1);
    gll16(vh + (size_t)sr0 * 2048 + j0 + sc0 * 8, (char*)Vl + wb0);
    gll16(vh + (size_t)sr1 * 2048 + j0 + sc0 * 8, (char*)Vl + wb1);
    // ---- E-band: fresh T-tiles nt=1..4 (nt=0 carried); overlaps staging ----
    float Bp[5][4];
#pragma unroll
    for (int r = 0; r < 4; r++) Bp[0][r] = Bpc[r];
    const int ebase = ebase00 + j0;
#pragma unroll
    for (int nt = 1; nt < 5; nt++) {
      int er = ebase + nt * 16 + l15;
      er = er > 2047 ? 2047 : er;  // clamped rows feed only masked entries
      const bf16* erow = Eb + (size_t)er * 64 + quad * 8;
      bf16x8 e0 = *(const bf16x8*)erow;
      bf16x8 e1 = *(const bf16x8*)(erow + 32);
      f32x4 zz = (f32x4){0.f, 0.f, 0.f, 0.f};
      zz = MFMA16(aq0, e0, zz);
      zz = MFMA16(aq1, e1, zz);
#pragma unroll
      for (int r = 0; r < 4; r++)
        Bp[nt][r] =
            __int_as_float(__builtin_amdgcn_ds_bpermute(bpaddr[r], __float_as_int(zz[r])));
    }
#pragma unroll
    for (int r = 0; r < 4; r++) Bpc[r] = Bp[4][r];

    __syncthreads();  // staging complete (vmcnt drained before barrier)
    // ---- S = q @ k^T from LDS (swizzled b128 reads) ----
    f32x4 s[4];
#pragma unroll
    for (int nt = 0; nt < 4; nt++) {
      int row = nt * 16 + l15;
      bf16x8 k0 = *(const bf16x8*)(Kl + ((row << 3) + (quad ^ (row & 7))) * 8);
      bf16x8 k1 = *(const bf16x8*)(Kl + ((row << 3) + ((quad + 4) ^ (row & 7))) * 8);
      f32x4 zz = (f32x4){0.f, 0.f, 0.f, 0.f};
      zz = MFMA16(aq0, k0, zz);
      s[nt] = MFMA16(aq1, k1, zz);
    }
    // ---- logits: skew add + scale (+ mask on diag tile) + exp2 + P ----
    if (diag) {
#pragma unroll
      for (int nt = 0; nt < 4; nt++)
#pragma unroll
        for (int r = 0; r < 4; r++) {
          int u = quad * 4 + r;
          int j = nt * 16 + l15;
          float skew = loA[r] ? Bp[nt][r] : Bp[nt + 1][r];
          float logit = (s[nt][r] + skew) * sc;
          if (j0 + j > i0 + u) logit = -1e30f;  // causal; exp2 -> 0
          Pw[u * 72 + j] = (bf16)EXP2F(logit);
        }
    } else {
#pragma unroll
      for (int nt = 0; nt < 4; nt++)
#pragma unroll
        for (int r = 0; r < 4; r++) {
          int u = quad * 4 + r;
          int j = nt * 16 + l15;
          float skew = loA[r] ? Bp[nt][r] : Bp[nt + 1][r];
          Pw[u * 72 + j] = (bf16)EXP2F((s[nt][r] + skew) * sc);
        }
    }
    // ---- PV: O += P @ V ; Osum += P @ ones ----
    bf16x8 pa0 = *(const bf16x8*)&Pw[l15 * 72 + quad * 8];
    bf16x8 pa1 = *(const bf16x8*)&Pw[l15 * 72 + 32 + quad * 8];
    Osum = MFMA16(pa0, ones, Osum);
    Osum = MFMA16(pa1, ones, Osum);
#pragma unroll
    for (int nt = 0; nt < 4; nt++) {
      int row = nt * 16 + l15;
      bf16x8 v0 = *(const bf16x8*)(Vl + ((row << 3) + (quad ^ (row & 7))) * 8);
      bf16x8 v1 = *(const bf16x8*)(Vl + ((row << 3) + ((quad + 4) ^ (row & 7))) * 8);
      O[nt] = MFMA16(pa0, v0, O[nt]);
      O[nt] = MFMA16(pa1, v1, O[nt]);
    }
  }
  // ---- epilogue: UNNORMALIZED partial O (bf16) + rowsum (f32) ----
  if (isB) {
    bf16* orow = Of1 + ((size_t)(bh * 1024 + (i0 - 1024))) * 64;
#pragma unroll
    for (int nt = 0; nt < 4; nt++)
#pragma unroll
      for (int r = 0; r < 4; r++)
        orow[(size_t)(quad * 4 + r) * 64 + nt * 16 + l15] = (bf16)O[nt][r];
    if (l15 == 0) {
#pragma unroll
      for (int r = 0; r < 4; r++) Os1[bh * 1024 + (i0 - 1024) + quad * 4 + r] = Osum[r];
    }
  } else {
    const int b = bh >> 3, hh = bh & 7;
    bf16* orow = attnb + ((size_t)(b * 2048 + i0)) * 512 + hh * 64;
#pragma unroll
    for (int nt = 0; nt < 4; nt++)
#pragma unroll
      for (int r = 0; r < 4; r++)
        orow[(size_t)(quad * 4 + r) * 512 + nt * 16 + l15] = (bf16)O[nt][r];
    if (l15 == 0) {
#pragma unroll
      for (int r = 0; r < 4; r++) Os0[bh * 2048 + i0 + quad * 4 + r] = Osum[r];
    }
  }
}

// ---------------------------------------------------------------------------
// normalize: attnb = (slot0 + slot1?) / (s0 + s1?), in place. vec8 per thread.
// ---------------------------------------------------------------------------
__global__ __launch_bounds__(256) void norm_kernel(bf16x8* __restrict__ attnb,
                                                   const bf16x8* __restrict__ Of1,
                                                   const float* __restrict__ Os0,
                                                   const float* __restrict__ Os1) {
  int i = blockIdx.x * 256 + threadIdx.x;  // vec8 index, 524288 total
  int col8 = i & 63;                       // 64 vec8 per row of 512
  int row = i >> 6;                        // b*2048 + l
  int b = row >> 11, l = row & 2047, h = col8 >> 3;
  int bh = b * 8 + h;
  float s = Os0[bh * 2048 + l];
  bf16x8 v0 = attnb[i];
  float acc[8];
#pragma unroll
  for (int j = 0; j < 8; j++) acc[j] = (float)v0[j];
  if (l >= 1024) {
    s += Os1[bh * 1024 + l - 1024];
    bf16x8 v1 = Of1[(size_t)(bh * 1024 + l - 1024) * 8 + (col8 & 7)];
#pragma unroll
    for (int j = 0; j < 8; j++) acc[j] += (float)v1[j];
  }
  float inv = 1.0f / s;
  bf16x8 o;
#pragma unroll
  for (int j = 0; j < 8; j++) o[j] = (bf16)(acc[j] * inv);
  attnb[i] = o;
}

// ---------------------------------------------------------------------------
extern "C" void kernel_launch(void* const* d_in, const int* in_sizes, int n_in,
                              void* d_out, int out_size, void* d_ws, size_t ws_size,
                              hipStream_t stream) {
  const float* Q = (const float*)d_in[0];
  const float* K = (const float*)d_in[1];
  const float* V = (const float*)d_in[2];
  const float* Wq = (const float*)d_in[4];
  const float* bq = (const float*)d_in[5];
  const float* Wk = (const float*)d_in[6];
  const float* bk = (const float*)d_in[7];
  const float* Wv = (const float*)d_in[8];
  const float* bv = (const float*)d_in[9];
  const float* fcw = (const float*)d_in[10];
  const float* fcb = (const float*)d_in[11];
  const float* E = (const float*)d_in[12];

  char* ws = (char*)d_ws;
  bf16* Xq = (bf16*)(ws + 0);
  bf16* Xk = (bf16*)(ws + 8388608);
  bf16* Xv = (bf16*)(ws + 16777216);
  bf16* Wqb = (bf16*)(ws + 25165824);
  bf16* Wkb = (bf16*)(ws + 25690112);
  bf16* Wvb = (bf16*)(ws + 26214400);
  bf16* fcwb = (bf16*)(ws + 26738688);
  bf16* Eb = (bf16*)(ws + 27262976);
  bf16* qbuf = (bf16*)(ws + 27525120);
  bf16* kbuf = (bf16*)(ws + 35913728);
  bf16* vTb = (bf16*)(ws + 44302336);   // old vbuf region: vT written directly
  bf16* Of1 = (bf16*)(ws + 52690944);   // 32*1024*64 bf16 = 4 MiB
  float* Os0 = (float*)(ws + 56885248); // 32*2048 f32 = 256 KiB
  float* Os1 = (float*)(ws + 57147392); // 32*1024 f32 = 128 KiB
  bf16* attnb = Xq;

  convert_all<<<13440, 256, 0, stream>>>(
      (const float4*)Q, (const float4*)K, (const float4*)V, (const float4*)Wq,
      (const float4*)Wk, (const float4*)Wv, (const float4*)fcw, (const float4*)E,
      (bf16x4*)Xq, (bf16x4*)Xk, (bf16x4*)Xv, (bf16x4*)Wqb, (bf16x4*)Wkb,
      (bf16x4*)Wvb, (bf16x4*)fcwb, (bf16x4*)Eb);

  proj_gemm<<<dim3(64, 8, 3), 256, 0, stream>>>(Xq, Xk, Xv, Wqb, Wkb, Wvb, bq, bk, bv,
                                                qbuf, kbuf, vTb);

  attn_kernel<<<1536, 256, 0, stream>>>(qbuf, kbuf, vTb, Eb, attnb, Of1, Os0, Os1);

  norm_kernel<<<2048, 256, 0, stream>>>((bf16x8*)attnb, (const bf16x8*)Of1, Os0, Os1);

  final_gemm<<<dim3(64, 8), 256, 0, stream>>>(attnb, fcwb, fcb, (float*)d_out);
}